// Round 3
// 240.249 us; speedup vs baseline: 1.0953x; 1.0953x over previous
//
#include <hip/hip_runtime.h>
#include <math.h>

// (B,I,H,O,A,M,R) = (16,256,512,256,1024,64,4), IF=471. All fp32.

__device__ __forceinline__ float sigf(float x){ return 1.0f/(1.0f+expf(-x)); }
__device__ __forceinline__ float softplusf(float x){ return fmaxf(x,0.0f)+log1pf(expf(-fabsf(x))); }

// ---------------- K1a: LSTM partial GEMM — grid (8,16,2), block 256 ----------------
__global__ __launch_bounds__(256) void k_lstm_part(const float* __restrict__ x,
    const float* __restrict__ rv, const float* __restrict__ hp,
    const float* __restrict__ Wx, const float* __restrict__ Wh,
    float* __restrict__ zpart){
  __shared__ float inp[8][64];
  int ct = blockIdx.x, kt = blockIdx.y, bg = blockIdx.z, t = threadIdx.x;
  for (int i = t; i < 512; i += 256){
    int bb = i >> 6, kk = i & 63;
    int k = kt*64 + kk, b = bg*8 + bb;
    float v = (k < 256) ? x[b*256+k] : (k < 512) ? rv[b*256 + k-256] : hp[b*512 + k-512];
    inp[bb][kk] = v;
  }
  __syncthreads();
  int col = ct*256 + t;
  float acc[8];
  #pragma unroll
  for (int bb = 0; bb < 8; ++bb) acc[bb] = 0.0f;
  for (int kk = 0; kk < 64; ++kk){
    int k = kt*64 + kk;
    float w = (k < 512) ? Wx[(long)k*2048 + col] : Wh[(long)(k-512)*2048 + col];
    #pragma unroll
    for (int bb = 0; bb < 8; ++bb) acc[bb] += inp[bb][kk]*w;
  }
  #pragma unroll
  for (int bb = 0; bb < 8; ++bb)
    zpart[((long)kt*16 + bg*8 + bb)*2048 + col] = acc[bb];
}

// ---------------- K1b: LSTM finish — grid (4 jt, 16 b), block 128 ----------------
__global__ void k_lstm_fin(const float* __restrict__ zpart, const float* __restrict__ bl,
                           const float* __restrict__ cp, float* __restrict__ h_ws){
  int jt = blockIdx.x, b = blockIdx.y, j = jt*128 + threadIdx.x;
  float zi = bl[j], zf = bl[512+j], zg = bl[1024+j], zo = bl[1536+j];
  for (int kt = 0; kt < 16; ++kt){
    const float* zp = zpart + ((long)kt*16 + b)*2048;
    zi += zp[j]; zf += zp[512+j]; zg += zp[1024+j]; zo += zp[1536+j];
  }
  float c = sigf(zf)*cp[b*512+j] + sigf(zi)*tanhf(zg);
  h_ws[b*512+j] = sigf(zo)*tanhf(c);
}

// ---------------- K2a: iface/out_hidden partial GEMM — grid (3,16,2), block 256 ----------------
__global__ __launch_bounds__(256) void k_iface_part(const float* __restrict__ h_ws,
    const float* __restrict__ W_if, const float* __restrict__ W_hid,
    float* __restrict__ ifpart){
  __shared__ float hh[8][32];
  int ct = blockIdx.x, kt = blockIdx.y, bg = blockIdx.z, t = threadIdx.x;
  {
    int bb = t >> 5, kk = t & 31;
    hh[bb][kk] = h_ws[(bg*8 + bb)*512 + kt*32 + kk];
  }
  __syncthreads();
  int col = ct*256 + t;
  float acc[8];
  #pragma unroll
  for (int bb = 0; bb < 8; ++bb) acc[bb] = 0.0f;
  if (col < 727){
    for (int kk = 0; kk < 32; ++kk){
      int k = kt*32 + kk;
      float w = (col < 471) ? W_if[(long)k*471 + col] : W_hid[(long)k*256 + (col-471)];
      #pragma unroll
      for (int bb = 0; bb < 8; ++bb) acc[bb] += hh[bb][kk]*w;
    }
    #pragma unroll
    for (int bb = 0; bb < 8; ++bb)
      ifpart[((long)kt*16 + bg*8 + bb)*768 + col] = acc[bb];
  }
}

// ---------------- K2b: iface finish — grid 16, block 768 ----------------
__global__ void k_iface_fin(const float* __restrict__ ifpart, const float* __restrict__ b_if,
                            const float* __restrict__ b_hid, float* __restrict__ ifr_ws,
                            float* __restrict__ outh_ws){
  int b = blockIdx.x, t = threadIdx.x;
  if (t >= 727) return;
  float s = (t < 471) ? b_if[t] : b_hid[t-471];
  for (int kt = 0; kt < 16; ++kt) s += ifpart[((long)kt*16 + b)*768 + t];
  if (t < 471) ifr_ws[b*512 + t] = s;
  else         outh_ws[b*256 + (t-471)] = s;
}

// ---------------- K3: FUSED activations + psi + usage + BITONIC sort + alloc — grid 16, block 1024 ----------------
// iface layout: k_r[0,256) beta_r[256,260) k_w[260,324) beta_w[324] erase[325,389)
//               write_v[389,453) free[453,457) g_a[457] g_w[458] pi[459,471)
// Sort: pack (order-preserving float bits, index) into uint64; 55-stage bitonic in LDS.
// Reproduces jnp.argsort stable ascending exactly (value asc, index tie-break), so the
// sorted value sequence -> cumprod -> alloc is bitwise identical to the rank-loop version.
__global__ void k_act_alloc(const float* __restrict__ ifr_ws, const float* __restrict__ rw_prev,
                            const float* __restrict__ ww_prev, const float* __restrict__ usage_prev,
                            float* __restrict__ ifa_ws, float* __restrict__ alloc_ws){
  __shared__ float sifa[480];
  __shared__ unsigned long long keys[1024];
  __shared__ float cpp[1024];
  int b = blockIdx.x, t = threadIdx.x;
  const float* ifr = ifr_ws + b*512;
  if (t < 471){
    float v = ifr[t], o = v;
    if ((t >= 256 && t < 260) || t == 324) o = 1.0f + softplusf(v);
    else if ((t >= 325 && t < 389) || (t >= 453 && t < 459)) o = sigf(v);
    sifa[t] = o;
  }
  __syncthreads();
  if (t < 4){
    float p0 = ifr[459+t*3+0], p1 = ifr[459+t*3+1], p2 = ifr[459+t*3+2];
    float mx = fmaxf(p0, fmaxf(p1,p2));
    float e0 = expf(p0-mx), e1 = expf(p1-mx), e2 = expf(p2-mx);
    float s = e0+e1+e2;
    sifa[459+t*3+0]=e0/s; sifa[459+t*3+1]=e1/s; sifa[459+t*3+2]=e2/s;
  }
  __syncthreads();
  if (t < 471) ifa_ws[b*512 + t] = sifa[t];
  float f0 = sifa[453], f1 = sifa[454], f2 = sifa[455], f3 = sifa[456];
  float psi = (1.f - f0*rw_prev[(long)(b*4+0)*1024 + t])
            * (1.f - f1*rw_prev[(long)(b*4+1)*1024 + t])
            * (1.f - f2*rw_prev[(long)(b*4+2)*1024 + t])
            * (1.f - f3*rw_prev[(long)(b*4+3)*1024 + t]);
  float uu = usage_prev[b*1024+t], w = ww_prev[b*1024+t];
  float uval = (uu + w - uu*w) * psi;
  // order-preserving float->uint transform (handles any sign, no NaN expected)
  unsigned int ub = __float_as_uint(uval);
  unsigned int k32 = ub ^ (((int)ub >> 31) | 0x80000000u);
  keys[t] = ((unsigned long long)k32 << 32) | (unsigned int)t;
  __syncthreads();
  // bitonic sort ascending, 1024 elements, 1024 threads (half active per stage)
  for (int k = 2; k <= 1024; k <<= 1){
    for (int j = k >> 1; j > 0; j >>= 1){
      int ixj = t ^ j;
      if (ixj > t){
        unsigned long long a = keys[t], c = keys[ixj];
        bool up = ((t & k) == 0);
        if ((a > c) == up){ keys[t] = c; keys[ixj] = a; }
      }
      __syncthreads();
    }
  }
  // unpack sorted (value, original index)
  unsigned long long key = keys[t];
  unsigned int hk = (unsigned int)(key >> 32);
  unsigned int ob = (hk & 0x80000000u) ? (hk ^ 0x80000000u) : ~hk;
  float su = __uint_as_float(ob);
  int oi = (int)(key & 1023u);
  // inclusive cumprod scan (Hillis-Steele), identical to previous version
  cpp[t] = su;
  __syncthreads();
  for (int off = 1; off < 1024; off <<= 1){
    float tmp = (t >= off) ? cpp[t-off] : 1.0f;
    __syncthreads();
    cpp[t] *= tmp;
    __syncthreads();
  }
  float cpe = (t == 0) ? 1.0f : cpp[t-1];
  alloc_ws[b*1024 + oi] = (1.0f - su) * cpe;
}

// ---------------- K4: write-content scores — grid (16 at,16 b), block 256 ----------------
__global__ __launch_bounds__(256) void k_wscore(const float* __restrict__ mem_prev,
    const float* __restrict__ ifa_ws, float* __restrict__ wsc_ws){
  int at = blockIdx.x, b = blockIdx.y;
  int t = threadIdx.x, w = t >> 6, m = t & 63;
  const float* ifa = ifa_ws + b*512;
  float kwm = ifa[260+m], beta = ifa[324];
  float knsq = kwm*kwm;
  for (int o = 32; o > 0; o >>= 1) knsq += __shfl_xor(knsq, o);
  float kn = sqrtf(knsq);
  for (int rr = 0; rr < 16; ++rr){
    int a = at*64 + w*16 + rr;
    float v = mem_prev[((long)b*1024+a)*64+m];
    float d = v*kwm, sq = v*v;
    for (int o = 32; o > 0; o >>= 1){ d += __shfl_xor(d,o); sq += __shfl_xor(sq,o); }
    if (m == 0) wsc_ws[b*1024+a] = beta*d/(kn*sqrtf(sq)+1e-6f);
  }
}

// ---------------- K5: softmax(wsc) + ww + e=ww*rw — grid 16, block 1024 ----------------
__global__ void k_cw_ww(const float* __restrict__ wsc_ws, const float* __restrict__ ifa_ws,
                        const float* __restrict__ alloc_ws, const float* __restrict__ rw_prev,
                        float* __restrict__ ww_ws, float* __restrict__ e_ws){
  __shared__ float red[1024];
  int b = blockIdx.x, t = threadIdx.x;
  const float* ifa = ifa_ws + b*512;
  float g_a = ifa[457], g_w = ifa[458];
  float sc = wsc_ws[b*1024+t];
  red[t] = sc; __syncthreads();
  for (int s = 512; s > 0; s >>= 1){ if (t < s) red[t] = fmaxf(red[t], red[t+s]); __syncthreads(); }
  float mx = red[0]; __syncthreads();
  float e = expf(sc - mx);
  red[t] = e; __syncthreads();
  for (int s = 512; s > 0; s >>= 1){ if (t < s) red[t] += red[t+s]; __syncthreads(); }
  float cw = e / red[0];
  float ww = g_w*(g_a*alloc_ws[b*1024+t] + (1.0f-g_a)*cw);
  ww_ws[b*1024+t] = ww;
  #pragma unroll
  for (int r = 0; r < 4; ++r)
    e_ws[(long)(b*4+r)*1024 + t] = ww * rw_prev[(long)(b*4+r)*1024 + t];
}

// ---------------- K6: updated-mem norms + 4 read-key dots (mem recomputed, not stored) ----------------
// grid (16 at, 16 b), block 256 = 4 waves x 16 rows
__global__ __launch_bounds__(256) void k_score(const float* __restrict__ mem_prev,
    const float* __restrict__ ww_ws, const float* __restrict__ ifa_ws,
    float* __restrict__ mnorm_ws, float* __restrict__ rdot_ws){
  int at = blockIdx.x, b = blockIdx.y;
  int t = threadIdx.x, w = t >> 6, m = t & 63;
  const float* ifa = ifa_ws + b*512;
  float er = ifa[325+m], wv = ifa[389+m];
  float k0 = ifa[m], k1 = ifa[64+m], k2 = ifa[128+m], k3 = ifa[192+m];
  for (int rr = 0; rr < 16; ++rr){
    int a = at*64 + w*16 + rr;
    float ww = ww_ws[b*1024+a];
    float v = mem_prev[((long)b*1024+a)*64+m]*(1.0f - ww*er) + ww*wv;
    float sq = v*v, d0 = v*k0, d1 = v*k1, d2 = v*k2, d3 = v*k3;
    for (int o = 32; o > 0; o >>= 1){
      sq += __shfl_xor(sq,o); d0 += __shfl_xor(d0,o); d1 += __shfl_xor(d1,o);
      d2 += __shfl_xor(d2,o); d3 += __shfl_xor(d3,o);
    }
    if (m == 0){
      mnorm_ws[b*1024+a] = sqrtf(sq);
      rdot_ws[(long)(b*4+0)*1024+a] = d0; rdot_ws[(long)(b*4+1)*1024+a] = d1;
      rdot_ws[(long)(b*4+2)*1024+a] = d2; rdot_ws[(long)(b*4+3)*1024+a] = d3;
    }
  }
}

// ---------------- K7a: link fwd/bwd via affine decomposition ----------------
// link = (1-ww_i-ww_j)L + ww_i p_j  (diag zeroed via correction)
// fwd[r,i] = (1-ww_i) SUM_j L a[r,j] - SUM_j L e[r,j] + ww_i SUM_j p_j a[r,j]   (a=rw, e=ww*rw)
// bwd[r,c] = (1-ww_c) SUM_i L a[r,i] - SUM_i L e[r,i] + p_c SUM_i e[r,i]
// grid (band 16, ct 16, b 16) = 4096 blocks, block 256 (wave = r, lane = row/col)
__global__ __launch_bounds__(256) void k_linkfb(const float* __restrict__ link_prev,
    const float* __restrict__ rw_prev, const float* __restrict__ e_ws,
    const float* __restrict__ prec_prev, const float* __restrict__ ww_ws,
    float* __restrict__ fwd_part, float* __restrict__ bwd_part){
  __shared__ float Lt[64][68];   // pad 68: 16B-aligned rows, conflict-free col reads
  int band = blockIdx.x, ct = blockIdx.y, b = blockIdx.z, t = threadIdx.x;
  int r = t >> 6, lane = t & 63;
  int ru = __builtin_amdgcn_readfirstlane(r);  // wave-uniform -> scalar loads below
  const float4* L4 = (const float4*)link_prev;
  #pragma unroll
  for (int q = 0; q < 4; ++q){
    int idx = t + 256*q;
    int row = idx >> 4, c4 = idx & 15;
    float4 v = L4[((long)b << 18) + (long)(band*64+row)*256 + ct*16 + c4];
    *(float4*)&Lt[row][c4*4] = v;
  }
  const float* aJ = rw_prev + (long)(b*4+ru)*1024 + ct*64;
  const float* eJ = e_ws    + (long)(b*4+ru)*1024 + ct*64;
  const float* aI = rw_prev + (long)(b*4+ru)*1024 + band*64;
  const float* eI = e_ws    + (long)(b*4+ru)*1024 + band*64;
  // tile-local scalars: Pt = sum_j p_j a[r,j]; Wt = sum_i e[r,i]
  float pv = prec_prev[b*1024 + ct*64 + lane] * aJ[lane];
  float wvs = eI[lane];
  for (int o = 32; o > 0; o >>= 1){ pv += __shfl_xor(pv,o); wvs += __shfl_xor(wvs,o); }
  float wwi = ww_ws[b*1024 + band*64 + lane];
  float wwc = ww_ws[b*1024 + ct*64 + lane];
  float pc  = prec_prev[b*1024 + ct*64 + lane];
  __syncthreads();
  // fwd: thread (r, row=lane)
  float A1 = 0.0f, A2 = 0.0f;
  for (int jc = 0; jc < 64; jc += 4){
    float4 Lv = *(const float4*)&Lt[lane][jc];
    A1 += Lv.x*aJ[jc] + Lv.y*aJ[jc+1] + Lv.z*aJ[jc+2] + Lv.w*aJ[jc+3];
    A2 += Lv.x*eJ[jc] + Lv.y*eJ[jc+1] + Lv.z*eJ[jc+2] + Lv.w*eJ[jc+3];
  }
  float facc = (1.0f - wwi)*A1 - A2 + wwi*pv;
  // bwd: thread (r, col=lane)
  float B1 = 0.0f, B2 = 0.0f;
  for (int rowl = 0; rowl < 64; ++rowl){
    float Lv = Lt[rowl][lane];
    B1 += Lv * aI[rowl];
    B2 += Lv * eI[rowl];
  }
  float bacc = (1.0f - wwc)*B1 - B2 + pc*wvs;
  if (band == ct){  // diagonal correction: formula included ((1-2ww)L + ww*p)*a at i==j
    float D = ((1.0f - 2.0f*wwi)*Lt[lane][lane] + wwi*pc)*aJ[lane];
    facc -= D;
    bacc -= D;
  }
  fwd_part[(long)ct*65536 + (long)(b*4+r)*1024 + band*64 + lane] = facc;
  bwd_part[(long)band*65536 + (long)(b*4+r)*1024 + ct*64 + lane] = bacc;
}

// ---------------- K7b: reduce partials — grid 64, block 1024 ----------------
__global__ void k_fbred(const float* __restrict__ fwd_part, const float* __restrict__ bwd_part,
                        float* __restrict__ fwd_ws, float* __restrict__ bwd_ws){
  int idx = blockIdx.x*1024 + threadIdx.x;
  float f = 0.0f, bsum = 0.0f;
  #pragma unroll
  for (int c = 0; c < 16; ++c){
    f    += fwd_part[(long)c*65536 + idx];
    bsum += bwd_part[(long)c*65536 + idx];
  }
  fwd_ws[idx] = f;
  bwd_ws[idx] = bsum;
}

// ---------------- K8: read softmax + mix + rv (mem recomputed) — grid (4,16), block 1024 ----------------
__global__ void k_read(const float* __restrict__ rdot_ws, const float* __restrict__ mnorm_ws,
                       const float* __restrict__ ifa_ws, const float* __restrict__ fwd_ws,
                       const float* __restrict__ bwd_ws, const float* __restrict__ mem_prev,
                       const float* __restrict__ ww_ws, float* __restrict__ rv_ws){
  __shared__ float red[1024]; __shared__ float wrs[1024]; __shared__ float wwsh[1024];
  __shared__ float par[1];
  int r = blockIdx.x, b = blockIdx.y, t = threadIdx.x; // a = t
  const float* ifa = ifa_ws + b*512;
  if (t == 0){
    float s = 0;
    for (int m = 0; m < 64; ++m){ float v = ifa[r*64+m]; s += v*v; }
    par[0] = sqrtf(s);
  }
  wwsh[t] = ww_ws[b*1024+t];
  __syncthreads();
  float kn = par[0], beta = ifa[256 + r];
  float sc = beta * rdot_ws[(long)(b*4+r)*1024 + t] / (kn*mnorm_ws[b*1024+t] + 1e-6f);
  red[t] = sc; __syncthreads();
  for (int s = 512; s > 0; s >>= 1){ if (t < s) red[t] = fmaxf(red[t], red[t+s]); __syncthreads(); }
  float mx = red[0]; __syncthreads();
  float e = expf(sc - mx);
  red[t] = e; __syncthreads();
  for (int s = 512; s > 0; s >>= 1){ if (t < s) red[t] += red[t+s]; __syncthreads(); }
  float cr = e / red[0];
  __syncthreads();
  float p0 = ifa[459+3*r], p1 = ifa[460+3*r], p2 = ifa[461+3*r];
  wrs[t] = p0*bwd_ws[(long)(b*4+r)*1024 + t] + p1*cr + p2*fwd_ws[(long)(b*4+r)*1024 + t];
  __syncthreads();
  int m = t & 63, ch = t >> 6;
  float er = ifa[325+m], wv = ifa[389+m];
  float acc = 0;
  for (int q = 0; q < 64; ++q){
    int a = ch*64 + q;
    float w = wwsh[a];
    float v = mem_prev[((long)b*1024 + a)*64 + m]*(1.0f - w*er) + w*wv;
    acc += wrs[a]*v;
  }
  red[ch*64 + m] = acc;
  __syncthreads();
  if (t < 64){
    float s = 0;
    for (int c2 = 0; c2 < 16; ++c2) s += red[c2*64 + t];
    rv_ws[(b*4+r)*64 + t] = s;
  }
}

// ---------------- K9: out = out_hidden + rv@W_rd + b_rd — grid 16, block 1024 (4-way K split) ----------------
__global__ void k_out(const float* __restrict__ outh_ws, const float* __restrict__ rv_ws,
                      const float* __restrict__ W_rd, const float* __restrict__ b_rd,
                      float* __restrict__ out){
  __shared__ float rvs[256]; __shared__ float part[4][256];
  int b = blockIdx.x, t = threadIdx.x;
  int o = t & 255, kq = t >> 8;
  if (t < 256) rvs[t] = rv_ws[b*256 + t];
  __syncthreads();
  float acc = 0.0f;
  for (int q = kq*64; q < kq*64 + 64; ++q) acc += rvs[q]*W_rd[(long)q*256 + o];
  part[kq][o] = acc;
  __syncthreads();
  if (t < 256)
    out[b*256+t] = outh_ws[b*256+t] + b_rd[t] + part[0][t] + part[1][t] + part[2][t] + part[3][t];
}

extern "C" void kernel_launch(void* const* d_in, const int* in_sizes, int n_in,
                              void* d_out, int out_size, void* d_ws, size_t ws_size,
                              hipStream_t stream){
  const float* x          = (const float*)d_in[0];
  const float* h_prev     = (const float*)d_in[1];
  const float* c_prev     = (const float*)d_in[2];
  const float* mem_prev   = (const float*)d_in[3];
  const float* rw_prev    = (const float*)d_in[4];
  const float* ww_prev    = (const float*)d_in[5];
  const float* usage_prev = (const float*)d_in[6];
  const float* prec_prev  = (const float*)d_in[7];
  const float* link_prev  = (const float*)d_in[8];
  const float* rv_prev    = (const float*)d_in[9];
  const float* Wx         = (const float*)d_in[10];
  const float* Wh         = (const float*)d_in[11];
  const float* b_lstm     = (const float*)d_in[12];
  const float* W_hid      = (const float*)d_in[13];
  const float* b_hid      = (const float*)d_in[14];
  const float* W_if       = (const float*)d_in[15];
  const float* b_if       = (const float*)d_in[16];
  const float* W_rd       = (const float*)d_in[17];
  const float* b_rd       = (const float*)d_in[18];
  float* out = (float*)d_out;

  // ws layout (floats), total 3178496 = 12.7 MB
  float* ws = (float*)d_ws;
  float* h_ws     = ws + 0;          // 8192
  float* ifr_ws   = ws + 8192;       // 8192
  float* ifa_ws   = ws + 16384;      // 8192
  float* outh_ws  = ws + 24576;      // 4096
  float* alloc_ws = ws + 28672;      // 16384
  float* ww_ws    = ws + 45056;      // 16384
  float* mnorm_ws = ws + 61440;      // 16384
  float* wsc_ws   = ws + 77824;      // 16384
  float* rv_ws    = ws + 94208;      // 4096
  float* fwd_ws   = ws + 98304;      // 65536
  float* bwd_ws   = ws + 163840;     // 65536
  float* rdot_ws  = ws + 229376;     // 65536
  float* e_ws     = ws + 294912;     // 65536
  float* zpart    = ws + 360448;     // 524288
  float* ifpart   = ws + 884736;     // 196608
  float* fwd_part = ws + 1081344;    // 1048576 (16 ct x 65536)
  float* bwd_part = ws + 2129920;    // 1048576 (16 band x 65536)

  k_lstm_part<<<dim3(8,16,2),256,0,stream>>>(x, rv_prev, h_prev, Wx, Wh, zpart);
  k_lstm_fin<<<dim3(4,16),128,0,stream>>>(zpart, b_lstm, c_prev, h_ws);
  k_iface_part<<<dim3(3,16,2),256,0,stream>>>(h_ws, W_if, W_hid, ifpart);
  k_iface_fin<<<16,768,0,stream>>>(ifpart, b_if, b_hid, ifr_ws, outh_ws);
  k_act_alloc<<<16,1024,0,stream>>>(ifr_ws, rw_prev, ww_prev, usage_prev, ifa_ws, alloc_ws);
  k_wscore<<<dim3(16,16),256,0,stream>>>(mem_prev, ifa_ws, wsc_ws);
  k_cw_ww<<<16,1024,0,stream>>>(wsc_ws, ifa_ws, alloc_ws, rw_prev, ww_ws, e_ws);
  k_score<<<dim3(16,16),256,0,stream>>>(mem_prev, ww_ws, ifa_ws, mnorm_ws, rdot_ws);
  k_linkfb<<<dim3(16,16,16),256,0,stream>>>(link_prev, rw_prev, e_ws, prec_prev, ww_ws,
                                            fwd_part, bwd_part);
  k_fbred<<<64,1024,0,stream>>>(fwd_part, bwd_part, fwd_ws, bwd_ws);
  k_read<<<dim3(4,16),1024,0,stream>>>(rdot_ws, mnorm_ws, ifa_ws, fwd_ws, bwd_ws,
                                       mem_prev, ww_ws, rv_ws);
  k_out<<<16,1024,0,stream>>>(outh_ws, rv_ws, W_rd, b_rd, out);
}

// Round 4
// 229.538 us; speedup vs baseline: 1.1464x; 1.0467x over previous
//
#include <hip/hip_runtime.h>
#include <math.h>

// (B,I,H,O,A,M,R) = (16,256,512,256,1024,64,4), IF=471. All fp32.

__device__ __forceinline__ float sigf(float x){ return 1.0f/(1.0f+expf(-x)); }
__device__ __forceinline__ float softplusf(float x){ return fmaxf(x,0.0f)+log1pf(expf(-fabsf(x))); }

// ---------------- K1a: LSTM partial GEMM — grid (8,16,2), block 256 ----------------
__global__ __launch_bounds__(256) void k_lstm_part(const float* __restrict__ x,
    const float* __restrict__ rv, const float* __restrict__ hp,
    const float* __restrict__ Wx, const float* __restrict__ Wh,
    float* __restrict__ zpart){
  __shared__ float inp[8][64];
  int ct = blockIdx.x, kt = blockIdx.y, bg = blockIdx.z, t = threadIdx.x;
  for (int i = t; i < 512; i += 256){
    int bb = i >> 6, kk = i & 63;
    int k = kt*64 + kk, b = bg*8 + bb;
    float v = (k < 256) ? x[b*256+k] : (k < 512) ? rv[b*256 + k-256] : hp[b*512 + k-512];
    inp[bb][kk] = v;
  }
  __syncthreads();
  int col = ct*256 + t;
  float acc[8];
  #pragma unroll
  for (int bb = 0; bb < 8; ++bb) acc[bb] = 0.0f;
  for (int kk = 0; kk < 64; ++kk){
    int k = kt*64 + kk;
    float w = (k < 512) ? Wx[(long)k*2048 + col] : Wh[(long)(k-512)*2048 + col];
    #pragma unroll
    for (int bb = 0; bb < 8; ++bb) acc[bb] += inp[bb][kk]*w;
  }
  #pragma unroll
  for (int bb = 0; bb < 8; ++bb)
    zpart[((long)kt*16 + bg*8 + bb)*2048 + col] = acc[bb];
}

// ---------------- K1b: LSTM finish — grid (4 jt, 16 b), block 128 ----------------
__global__ void k_lstm_fin(const float* __restrict__ zpart, const float* __restrict__ bl,
                           const float* __restrict__ cp, float* __restrict__ h_ws){
  int jt = blockIdx.x, b = blockIdx.y, j = jt*128 + threadIdx.x;
  float zi = bl[j], zf = bl[512+j], zg = bl[1024+j], zo = bl[1536+j];
  for (int kt = 0; kt < 16; ++kt){
    const float* zp = zpart + ((long)kt*16 + b)*2048;
    zi += zp[j]; zf += zp[512+j]; zg += zp[1024+j]; zo += zp[1536+j];
  }
  float c = sigf(zf)*cp[b*512+j] + sigf(zi)*tanhf(zg);
  h_ws[b*512+j] = sigf(zo)*tanhf(c);
}

// ---------------- K2a: iface/out_hidden partial GEMM — grid (3,16,2), block 256 ----------------
__global__ __launch_bounds__(256) void k_iface_part(const float* __restrict__ h_ws,
    const float* __restrict__ W_if, const float* __restrict__ W_hid,
    float* __restrict__ ifpart){
  __shared__ float hh[8][32];
  int ct = blockIdx.x, kt = blockIdx.y, bg = blockIdx.z, t = threadIdx.x;
  {
    int bb = t >> 5, kk = t & 31;
    hh[bb][kk] = h_ws[(bg*8 + bb)*512 + kt*32 + kk];
  }
  __syncthreads();
  int col = ct*256 + t;
  float acc[8];
  #pragma unroll
  for (int bb = 0; bb < 8; ++bb) acc[bb] = 0.0f;
  if (col < 727){
    for (int kk = 0; kk < 32; ++kk){
      int k = kt*32 + kk;
      float w = (col < 471) ? W_if[(long)k*471 + col] : W_hid[(long)k*256 + (col-471)];
      #pragma unroll
      for (int bb = 0; bb < 8; ++bb) acc[bb] += hh[bb][kk]*w;
    }
    #pragma unroll
    for (int bb = 0; bb < 8; ++bb)
      ifpart[((long)kt*16 + bg*8 + bb)*768 + col] = acc[bb];
  }
}

// ---------------- K2b: iface finish — grid 16, block 768 ----------------
__global__ void k_iface_fin(const float* __restrict__ ifpart, const float* __restrict__ b_if,
                            const float* __restrict__ b_hid, float* __restrict__ ifr_ws,
                            float* __restrict__ outh_ws){
  int b = blockIdx.x, t = threadIdx.x;
  if (t >= 727) return;
  float s = (t < 471) ? b_if[t] : b_hid[t-471];
  for (int kt = 0; kt < 16; ++kt) s += ifpart[((long)kt*16 + b)*768 + t];
  if (t < 471) ifr_ws[b*512 + t] = s;
  else         outh_ws[b*256 + (t-471)] = s;
}

// ---------------- K3: FUSED activations + psi + usage + register BITONIC + alloc — grid 16, block 1024 ----------------
// iface layout: k_r[0,256) beta_r[256,260) k_w[260,324) beta_w[324] erase[325,389)
//               write_v[389,453) free[453,457) g_a[457] g_w[458] pi[459,471)
// Bitonic network identical to LDS version (bit-identical sort output); 45 of 55 stages
// are within-wave -> shfl_xor (no barrier); 10 cross-wave stages use LDS.
// Cumprod: wave shfl-scan + 16 wave-totals (2 barriers) instead of 20-barrier Hillis-Steele.
__global__ void k_act_alloc(const float* __restrict__ ifr_ws, const float* __restrict__ rw_prev,
                            const float* __restrict__ ww_prev, const float* __restrict__ usage_prev,
                            float* __restrict__ ifa_ws, float* __restrict__ alloc_ws){
  __shared__ float sifa[480];
  __shared__ unsigned long long keys[1024];
  __shared__ float wtot[16];
  int b = blockIdx.x, t = threadIdx.x;
  int lane = t & 63, wid = t >> 6;
  const float* ifr = ifr_ws + b*512;
  if (t < 471){
    float v = ifr[t], o = v;
    if ((t >= 256 && t < 260) || t == 324) o = 1.0f + softplusf(v);
    else if ((t >= 325 && t < 389) || (t >= 453 && t < 459)) o = sigf(v);
    sifa[t] = o;
  }
  __syncthreads();
  if (t < 4){
    float p0 = ifr[459+t*3+0], p1 = ifr[459+t*3+1], p2 = ifr[459+t*3+2];
    float mx = fmaxf(p0, fmaxf(p1,p2));
    float e0 = expf(p0-mx), e1 = expf(p1-mx), e2 = expf(p2-mx);
    float s = e0+e1+e2;
    sifa[459+t*3+0]=e0/s; sifa[459+t*3+1]=e1/s; sifa[459+t*3+2]=e2/s;
  }
  __syncthreads();
  if (t < 471) ifa_ws[b*512 + t] = sifa[t];
  float f0 = sifa[453], f1 = sifa[454], f2 = sifa[455], f3 = sifa[456];
  float psi = (1.f - f0*rw_prev[(long)(b*4+0)*1024 + t])
            * (1.f - f1*rw_prev[(long)(b*4+1)*1024 + t])
            * (1.f - f2*rw_prev[(long)(b*4+2)*1024 + t])
            * (1.f - f3*rw_prev[(long)(b*4+3)*1024 + t]);
  float uu = usage_prev[b*1024+t], w = ww_prev[b*1024+t];
  float uval = (uu + w - uu*w) * psi;
  // order-preserving float->uint transform
  unsigned int ub = __float_as_uint(uval);
  unsigned int k32 = ub ^ (((int)ub >> 31) | 0x80000000u);
  unsigned long long key = ((unsigned long long)k32 << 32) | (unsigned int)t;
  // bitonic sort ascending, keys in registers; same compare-exchange network as before
  for (int kk2 = 2; kk2 <= 1024; kk2 <<= 1){
    for (int j = kk2 >> 1; j > 0; j >>= 1){
      unsigned long long other;
      if (j >= 64){               // cross-wave: LDS route (uniform branch)
        keys[t] = key;
        __syncthreads();
        other = keys[t ^ j];
        __syncthreads();
      } else {                    // within-wave: shfl, no barrier
        other = __shfl_xor(key, j);
      }
      bool up = ((t & kk2) == 0);
      bool keepMin = (((t & j) == 0) == up);
      if (keepMin ? (other < key) : (other > key)) key = other;
    }
  }
  // unpack sorted (value, original index); thread t holds sorted position t
  unsigned int hk = (unsigned int)(key >> 32);
  unsigned int ob = (hk & 0x80000000u) ? (hk ^ 0x80000000u) : ~hk;
  float su = __uint_as_float(ob);
  int oi = (int)(key & 1023u);
  // inclusive cumprod: wave shfl-scan, then wave-total prefix
  float s = su;
  #pragma unroll
  for (int off = 1; off < 64; off <<= 1){
    float v = __shfl_up(s, off);
    if (lane >= off) s *= v;
  }
  if (lane == 63) wtot[wid] = s;
  __syncthreads();
  float wpre = 1.0f;
  for (int w2 = 0; w2 < wid; ++w2) wpre *= wtot[w2];
  float ex = __shfl_up(s, 1);
  if (lane == 0) ex = 1.0f;
  float cpe = ex * wpre;          // product of su[0..t-1]
  alloc_ws[b*1024 + oi] = (1.0f - su) * cpe;
}

// ---------------- K4: write-content scores — grid (16 at,16 b), block 512 (8 waves x 8 rows) ----------------
__global__ __launch_bounds__(512) void k_wscore(const float* __restrict__ mem_prev,
    const float* __restrict__ ifa_ws, float* __restrict__ wsc_ws){
  int at = blockIdx.x, b = blockIdx.y;
  int t = threadIdx.x, w = t >> 6, m = t & 63;
  const float* ifa = ifa_ws + b*512;
  float kwm = ifa[260+m], beta = ifa[324];
  float knsq = kwm*kwm;
  for (int o = 32; o > 0; o >>= 1) knsq += __shfl_xor(knsq, o);
  float kn = sqrtf(knsq);
  for (int rr = 0; rr < 8; ++rr){
    int a = at*64 + w*8 + rr;
    float v = mem_prev[((long)b*1024+a)*64+m];
    float d = v*kwm, sq = v*v;
    for (int o = 32; o > 0; o >>= 1){ d += __shfl_xor(d,o); sq += __shfl_xor(sq,o); }
    if (m == 0) wsc_ws[b*1024+a] = beta*d/(kn*sqrtf(sq)+1e-6f);
  }
}

// ---------------- K5: softmax(wsc) + ww + e=ww*rw — grid 16, block 1024 (wave reduce) ----------------
__global__ void k_cw_ww(const float* __restrict__ wsc_ws, const float* __restrict__ ifa_ws,
                        const float* __restrict__ alloc_ws, const float* __restrict__ rw_prev,
                        float* __restrict__ ww_ws, float* __restrict__ e_ws){
  __shared__ float wred[16]; __shared__ float wred2[16];
  int b = blockIdx.x, t = threadIdx.x, lane = t & 63, wid = t >> 6;
  const float* ifa = ifa_ws + b*512;
  float g_a = ifa[457], g_w = ifa[458];
  float sc = wsc_ws[b*1024+t];
  float m = sc;
  for (int o = 32; o > 0; o >>= 1) m = fmaxf(m, __shfl_xor(m, o));
  if (lane == 0) wred[wid] = m;
  __syncthreads();
  float mx = wred[0];
  #pragma unroll
  for (int i = 1; i < 16; ++i) mx = fmaxf(mx, wred[i]);
  float e = expf(sc - mx);
  float ssum = e;
  for (int o = 32; o > 0; o >>= 1) ssum += __shfl_xor(ssum, o);
  if (lane == 0) wred2[wid] = ssum;
  __syncthreads();
  float tot = 0.0f;
  #pragma unroll
  for (int i = 0; i < 16; ++i) tot += wred2[i];
  float cw = e / tot;
  float ww = g_w*(g_a*alloc_ws[b*1024+t] + (1.0f-g_a)*cw);
  ww_ws[b*1024+t] = ww;
  #pragma unroll
  for (int r = 0; r < 4; ++r)
    e_ws[(long)(b*4+r)*1024 + t] = ww * rw_prev[(long)(b*4+r)*1024 + t];
}

// ---------------- K6: updated-mem norms + 4 read-key dots — grid (16 at, 16 b), block 512 (8 waves x 8 rows) ----------------
__global__ __launch_bounds__(512) void k_score(const float* __restrict__ mem_prev,
    const float* __restrict__ ww_ws, const float* __restrict__ ifa_ws,
    float* __restrict__ mnorm_ws, float* __restrict__ rdot_ws){
  int at = blockIdx.x, b = blockIdx.y;
  int t = threadIdx.x, w = t >> 6, m = t & 63;
  const float* ifa = ifa_ws + b*512;
  float er = ifa[325+m], wv = ifa[389+m];
  float k0 = ifa[m], k1 = ifa[64+m], k2 = ifa[128+m], k3 = ifa[192+m];
  for (int rr = 0; rr < 8; ++rr){
    int a = at*64 + w*8 + rr;
    float ww = ww_ws[b*1024+a];
    float v = mem_prev[((long)b*1024+a)*64+m]*(1.0f - ww*er) + ww*wv;
    float sq = v*v, d0 = v*k0, d1 = v*k1, d2 = v*k2, d3 = v*k3;
    for (int o = 32; o > 0; o >>= 1){
      sq += __shfl_xor(sq,o); d0 += __shfl_xor(d0,o); d1 += __shfl_xor(d1,o);
      d2 += __shfl_xor(d2,o); d3 += __shfl_xor(d3,o);
    }
    if (m == 0){
      mnorm_ws[b*1024+a] = sqrtf(sq);
      rdot_ws[(long)(b*4+0)*1024+a] = d0; rdot_ws[(long)(b*4+1)*1024+a] = d1;
      rdot_ws[(long)(b*4+2)*1024+a] = d2; rdot_ws[(long)(b*4+3)*1024+a] = d3;
    }
  }
}

// ---------------- K7a: link fwd/bwd via affine decomposition ----------------
// link = (1-ww_i-ww_j)L + ww_i p_j  (diag zeroed via correction)
// fwd[r,i] = (1-ww_i) SUM_j L a[r,j] - SUM_j L e[r,j] + ww_i SUM_j p_j a[r,j]   (a=rw, e=ww*rw)
// bwd[r,c] = (1-ww_c) SUM_i L a[r,i] - SUM_i L e[r,i] + p_c SUM_i e[r,i]
// grid (band 16, ct 16, b 16) = 4096 blocks, block 256 (wave = r, lane = row/col)
__global__ __launch_bounds__(256) void k_linkfb(const float* __restrict__ link_prev,
    const float* __restrict__ rw_prev, const float* __restrict__ e_ws,
    const float* __restrict__ prec_prev, const float* __restrict__ ww_ws,
    float* __restrict__ fwd_part, float* __restrict__ bwd_part){
  __shared__ float Lt[64][68];   // pad 68: 16B-aligned rows, conflict-free col reads
  int band = blockIdx.x, ct = blockIdx.y, b = blockIdx.z, t = threadIdx.x;
  int r = t >> 6, lane = t & 63;
  int ru = __builtin_amdgcn_readfirstlane(r);  // wave-uniform -> scalar loads below
  const float4* L4 = (const float4*)link_prev;
  #pragma unroll
  for (int q = 0; q < 4; ++q){
    int idx = t + 256*q;
    int row = idx >> 4, c4 = idx & 15;
    float4 v = L4[((long)b << 18) + (long)(band*64+row)*256 + ct*16 + c4];
    *(float4*)&Lt[row][c4*4] = v;
  }
  const float* aJ = rw_prev + (long)(b*4+ru)*1024 + ct*64;
  const float* eJ = e_ws    + (long)(b*4+ru)*1024 + ct*64;
  const float* aI = rw_prev + (long)(b*4+ru)*1024 + band*64;
  const float* eI = e_ws    + (long)(b*4+ru)*1024 + band*64;
  // tile-local scalars: Pt = sum_j p_j a[r,j]; Wt = sum_i e[r,i]
  float pv = prec_prev[b*1024 + ct*64 + lane] * aJ[lane];
  float wvs = eI[lane];
  for (int o = 32; o > 0; o >>= 1){ pv += __shfl_xor(pv,o); wvs += __shfl_xor(wvs,o); }
  float wwi = ww_ws[b*1024 + band*64 + lane];
  float wwc = ww_ws[b*1024 + ct*64 + lane];
  float pc  = prec_prev[b*1024 + ct*64 + lane];
  __syncthreads();
  // fwd: thread (r, row=lane)
  float A1 = 0.0f, A2 = 0.0f;
  for (int jc = 0; jc < 64; jc += 4){
    float4 Lv = *(const float4*)&Lt[lane][jc];
    A1 += Lv.x*aJ[jc] + Lv.y*aJ[jc+1] + Lv.z*aJ[jc+2] + Lv.w*aJ[jc+3];
    A2 += Lv.x*eJ[jc] + Lv.y*eJ[jc+1] + Lv.z*eJ[jc+2] + Lv.w*eJ[jc+3];
  }
  float facc = (1.0f - wwi)*A1 - A2 + wwi*pv;
  // bwd: thread (r, col=lane)
  float B1 = 0.0f, B2 = 0.0f;
  for (int rowl = 0; rowl < 64; ++rowl){
    float Lv = Lt[rowl][lane];
    B1 += Lv * aI[rowl];
    B2 += Lv * eI[rowl];
  }
  float bacc = (1.0f - wwc)*B1 - B2 + pc*wvs;
  if (band == ct){  // diagonal correction: formula included ((1-2ww)L + ww*p)*a at i==j
    float D = ((1.0f - 2.0f*wwi)*Lt[lane][lane] + wwi*pc)*aJ[lane];
    facc -= D;
    bacc -= D;
  }
  fwd_part[(long)ct*65536 + (long)(b*4+r)*1024 + band*64 + lane] = facc;
  bwd_part[(long)band*65536 + (long)(b*4+r)*1024 + ct*64 + lane] = bacc;
}

// ---------------- K8: read softmax + mix + rv (mem recomputed; fbred folded in) — grid (4,16), block 1024 ----------------
__global__ void k_read(const float* __restrict__ rdot_ws, const float* __restrict__ mnorm_ws,
                       const float* __restrict__ ifa_ws, const float* __restrict__ fwd_part,
                       const float* __restrict__ bwd_part, const float* __restrict__ mem_prev,
                       const float* __restrict__ ww_ws, float* __restrict__ rv_ws){
  __shared__ float red[1024]; __shared__ float wrs[1024]; __shared__ float wwsh[1024];
  __shared__ float par[1]; __shared__ float wred[16]; __shared__ float wred2[16];
  int r = blockIdx.x, b = blockIdx.y, t = threadIdx.x; // a = t
  int lane = t & 63, wid = t >> 6;
  const float* ifa = ifa_ws + b*512;
  long base = (long)(b*4+r)*1024 + t;
  // folded k_fbred: 16-way partial sums (coalesced)
  float fsum = 0.0f, bsum = 0.0f;
  #pragma unroll
  for (int c = 0; c < 16; ++c){
    fsum += fwd_part[(long)c*65536 + base];
    bsum += bwd_part[(long)c*65536 + base];
  }
  // parallel read-key norm (wave 0)
  if (t < 64){
    float v = ifa[r*64+t];
    float sq = v*v;
    for (int o = 32; o > 0; o >>= 1) sq += __shfl_xor(sq, o);
    if (t == 0) par[0] = sqrtf(sq);
  }
  wwsh[t] = ww_ws[b*1024+t];
  __syncthreads();
  float kn = par[0], beta = ifa[256 + r];
  float sc = beta * rdot_ws[base] / (kn*mnorm_ws[b*1024+t] + 1e-6f);
  // wave-reduce max
  float m = sc;
  for (int o = 32; o > 0; o >>= 1) m = fmaxf(m, __shfl_xor(m, o));
  if (lane == 0) wred[wid] = m;
  __syncthreads();
  float mx = wred[0];
  #pragma unroll
  for (int i = 1; i < 16; ++i) mx = fmaxf(mx, wred[i]);
  float e = expf(sc - mx);
  // wave-reduce sum
  float s = e;
  for (int o = 32; o > 0; o >>= 1) s += __shfl_xor(s, o);
  if (lane == 0) wred2[wid] = s;
  __syncthreads();
  float tot = 0.0f;
  #pragma unroll
  for (int i = 0; i < 16; ++i) tot += wred2[i];
  float cr = e / tot;
  float p0 = ifa[459+3*r], p1 = ifa[460+3*r], p2 = ifa[461+3*r];
  wrs[t] = p0*bsum + p1*cr + p2*fsum;
  __syncthreads();
  int mm = t & 63, ch = t >> 6;
  float er = ifa[325+mm], wv = ifa[389+mm];
  float acc = 0;
  for (int q = 0; q < 64; ++q){
    int a = ch*64 + q;
    float w = wwsh[a];
    float v = mem_prev[((long)b*1024 + a)*64 + mm]*(1.0f - w*er) + w*wv;
    acc += wrs[a]*v;
  }
  red[ch*64 + mm] = acc;
  __syncthreads();
  if (t < 64){
    float s2 = 0;
    for (int c2 = 0; c2 < 16; ++c2) s2 += red[c2*64 + t];
    rv_ws[(b*4+r)*64 + t] = s2;
  }
}

// ---------------- K9: out = out_hidden + rv@W_rd + b_rd — grid 16, block 1024 (4-way K split) ----------------
__global__ void k_out(const float* __restrict__ outh_ws, const float* __restrict__ rv_ws,
                      const float* __restrict__ W_rd, const float* __restrict__ b_rd,
                      float* __restrict__ out){
  __shared__ float rvs[256]; __shared__ float part[4][256];
  int b = blockIdx.x, t = threadIdx.x;
  int o = t & 255, kq = t >> 8;
  if (t < 256) rvs[t] = rv_ws[b*256 + t];
  __syncthreads();
  float acc = 0.0f;
  for (int q = kq*64; q < kq*64 + 64; ++q) acc += rvs[q]*W_rd[(long)q*256 + o];
  part[kq][o] = acc;
  __syncthreads();
  if (t < 256)
    out[b*256+t] = outh_ws[b*256+t] + b_rd[t] + part[0][t] + part[1][t] + part[2][t] + part[3][t];
}

extern "C" void kernel_launch(void* const* d_in, const int* in_sizes, int n_in,
                              void* d_out, int out_size, void* d_ws, size_t ws_size,
                              hipStream_t stream){
  const float* x          = (const float*)d_in[0];
  const float* h_prev     = (const float*)d_in[1];
  const float* c_prev     = (const float*)d_in[2];
  const float* mem_prev   = (const float*)d_in[3];
  const float* rw_prev    = (const float*)d_in[4];
  const float* ww_prev    = (const float*)d_in[5];
  const float* usage_prev = (const float*)d_in[6];
  const float* prec_prev  = (const float*)d_in[7];
  const float* link_prev  = (const float*)d_in[8];
  const float* rv_prev    = (const float*)d_in[9];
  const float* Wx         = (const float*)d_in[10];
  const float* Wh         = (const float*)d_in[11];
  const float* b_lstm     = (const float*)d_in[12];
  const float* W_hid      = (const float*)d_in[13];
  const float* b_hid      = (const float*)d_in[14];
  const float* W_if       = (const float*)d_in[15];
  const float* b_if       = (const float*)d_in[16];
  const float* W_rd       = (const float*)d_in[17];
  const float* b_rd       = (const float*)d_in[18];
  float* out = (float*)d_out;

  // ws layout (floats), total 3178496 = 12.7 MB
  float* ws = (float*)d_ws;
  float* h_ws     = ws + 0;          // 8192
  float* ifr_ws   = ws + 8192;       // 8192
  float* ifa_ws   = ws + 16384;      // 8192
  float* outh_ws  = ws + 24576;      // 4096
  float* alloc_ws = ws + 28672;      // 16384
  float* ww_ws    = ws + 45056;      // 16384
  float* mnorm_ws = ws + 61440;      // 16384
  float* wsc_ws   = ws + 77824;      // 16384
  float* rv_ws    = ws + 94208;      // 4096
  float* fwd_ws   = ws + 98304;      // 65536 (unused, kept for layout stability)
  float* bwd_ws   = ws + 163840;     // 65536 (unused, kept for layout stability)
  float* rdot_ws  = ws + 229376;     // 65536
  float* e_ws     = ws + 294912;     // 65536
  float* zpart    = ws + 360448;     // 524288
  float* ifpart   = ws + 884736;     // 196608
  float* fwd_part = ws + 1081344;    // 1048576 (16 ct x 65536)
  float* bwd_part = ws + 2129920;    // 1048576 (16 band x 65536)
  (void)fwd_ws; (void)bwd_ws;

  k_lstm_part<<<dim3(8,16,2),256,0,stream>>>(x, rv_prev, h_prev, Wx, Wh, zpart);
  k_lstm_fin<<<dim3(4,16),128,0,stream>>>(zpart, b_lstm, c_prev, h_ws);
  k_iface_part<<<dim3(3,16,2),256,0,stream>>>(h_ws, W_if, W_hid, ifpart);
  k_iface_fin<<<16,768,0,stream>>>(ifpart, b_if, b_hid, ifr_ws, outh_ws);
  k_act_alloc<<<16,1024,0,stream>>>(ifr_ws, rw_prev, ww_prev, usage_prev, ifa_ws, alloc_ws);
  k_wscore<<<dim3(16,16),512,0,stream>>>(mem_prev, ifa_ws, wsc_ws);
  k_cw_ww<<<16,1024,0,stream>>>(wsc_ws, ifa_ws, alloc_ws, rw_prev, ww_ws, e_ws);
  k_score<<<dim3(16,16),512,0,stream>>>(mem_prev, ww_ws, ifa_ws, mnorm_ws, rdot_ws);
  k_linkfb<<<dim3(16,16,16),256,0,stream>>>(link_prev, rw_prev, e_ws, prec_prev, ww_ws,
                                            fwd_part, bwd_part);
  k_read<<<dim3(4,16),1024,0,stream>>>(rdot_ws, mnorm_ws, ifa_ws, fwd_part, bwd_part,
                                       mem_prev, ww_ws, rv_ws);
  k_out<<<16,1024,0,stream>>>(outh_ws, rv_ws, W_rd, b_rd, out);
}

// Round 5
// 229.449 us; speedup vs baseline: 1.1468x; 1.0004x over previous
//
#include <hip/hip_runtime.h>
#include <math.h>

// (B,I,H,O,A,M,R) = (16,256,512,256,1024,64,4), IF=471. All fp32.

__device__ __forceinline__ float sigf(float x){ return 1.0f/(1.0f+expf(-x)); }
__device__ __forceinline__ float softplusf(float x){ return fmaxf(x,0.0f)+log1pf(expf(-fabsf(x))); }

// ---------------- K1a: LSTM partial GEMM — grid (8 ct,16 kt), block 256, all 16 batches ----------------
// bg merged: weights read ONCE (8.4 MB instead of 16.8), acc[16] registers.
__global__ __launch_bounds__(256) void k_lstm_part(const float* __restrict__ x,
    const float* __restrict__ rv, const float* __restrict__ hp,
    const float* __restrict__ Wx, const float* __restrict__ Wh,
    float* __restrict__ zpart){
  __shared__ float inp[16][64];
  int ct = blockIdx.x, kt = blockIdx.y, t = threadIdx.x;
  #pragma unroll
  for (int q = 0; q < 4; ++q){
    int i = t + 256*q;
    int bb = i >> 6, kk = i & 63;
    int k = kt*64 + kk;
    float v = (k < 256) ? x[bb*256+k] : (k < 512) ? rv[bb*256 + k-256] : hp[bb*512 + k-512];
    inp[bb][kk] = v;
  }
  __syncthreads();
  int col = ct*256 + t;
  float acc[16];
  #pragma unroll
  for (int bb = 0; bb < 16; ++bb) acc[bb] = 0.0f;
  for (int kk = 0; kk < 64; ++kk){
    int k = kt*64 + kk;
    float w = (k < 512) ? Wx[(long)k*2048 + col] : Wh[(long)(k-512)*2048 + col];
    #pragma unroll
    for (int bb = 0; bb < 16; ++bb) acc[bb] += inp[bb][kk]*w;
  }
  #pragma unroll
  for (int bb = 0; bb < 16; ++bb)
    zpart[((long)kt*16 + bb)*2048 + col] = acc[bb];
}

// ---------------- K1b: LSTM finish — grid (4 jt, 16 b), block 128 ----------------
__global__ void k_lstm_fin(const float* __restrict__ zpart, const float* __restrict__ bl,
                           const float* __restrict__ cp, float* __restrict__ h_ws){
  int jt = blockIdx.x, b = blockIdx.y, j = jt*128 + threadIdx.x;
  float zi = bl[j], zf = bl[512+j], zg = bl[1024+j], zo = bl[1536+j];
  for (int kt = 0; kt < 16; ++kt){
    const float* zp = zpart + ((long)kt*16 + b)*2048;
    zi += zp[j]; zf += zp[512+j]; zg += zp[1024+j]; zo += zp[1536+j];
  }
  float c = sigf(zf)*cp[b*512+j] + sigf(zi)*tanhf(zg);
  h_ws[b*512+j] = sigf(zo)*tanhf(c);
}

// ---------------- K2a: iface/out_hidden partial GEMM — grid (3 ct,16 kt), block 256, all 16 batches ----------------
__global__ __launch_bounds__(256) void k_iface_part(const float* __restrict__ h_ws,
    const float* __restrict__ W_if, const float* __restrict__ W_hid,
    float* __restrict__ ifpart){
  __shared__ float hh[16][32];
  int ct = blockIdx.x, kt = blockIdx.y, t = threadIdx.x;
  #pragma unroll
  for (int q = 0; q < 2; ++q){
    int i = t + 256*q;
    int bb = i >> 5, kk = i & 31;
    hh[bb][kk] = h_ws[bb*512 + kt*32 + kk];
  }
  __syncthreads();
  int col = ct*256 + t;
  float acc[16];
  #pragma unroll
  for (int bb = 0; bb < 16; ++bb) acc[bb] = 0.0f;
  if (col < 727){
    for (int kk = 0; kk < 32; ++kk){
      int k = kt*32 + kk;
      float w = (col < 471) ? W_if[(long)k*471 + col] : W_hid[(long)k*256 + (col-471)];
      #pragma unroll
      for (int bb = 0; bb < 16; ++bb) acc[bb] += hh[bb][kk]*w;
    }
    #pragma unroll
    for (int bb = 0; bb < 16; ++bb)
      ifpart[((long)kt*16 + bb)*768 + col] = acc[bb];
  }
}

// ---------------- K3: FUSED iface-finish + activations + psi + usage + register BITONIC + alloc ----------------
// grid 16, block 1024. Absorbs former k_iface_fin (727-col partial-sum) — no ifr_ws round trip.
// iface layout: k_r[0,256) beta_r[256,260) k_w[260,324) beta_w[324] erase[325,389)
//               write_v[389,453) free[453,457) g_a[457] g_w[458] pi[459,471)
__global__ __launch_bounds__(1024) void k_actfa(const float* __restrict__ ifpart,
                            const float* __restrict__ b_if, const float* __restrict__ b_hid,
                            const float* __restrict__ rw_prev,
                            const float* __restrict__ ww_prev, const float* __restrict__ usage_prev,
                            float* __restrict__ outh_ws,
                            float* __restrict__ ifa_ws, float* __restrict__ alloc_ws){
  __shared__ float sraw[480];
  __shared__ float sifa[480];
  __shared__ unsigned long long keys[1024];
  __shared__ float wtot[16];
  int b = blockIdx.x, t = threadIdx.x;
  int lane = t & 63, wid = t >> 6;
  // former k_iface_fin: sum 16 K-partials + bias
  if (t < 727){
    float s = (t < 471) ? b_if[t] : b_hid[t-471];
    #pragma unroll
    for (int kt = 0; kt < 16; ++kt) s += ifpart[((long)kt*16 + b)*768 + t];
    if (t < 471) sraw[t] = s;
    else         outh_ws[b*256 + (t-471)] = s;
  }
  __syncthreads();
  // activations (disjoint writers: t<459 generic, t<4 handles pi block)
  if (t < 459){
    float v = sraw[t], o = v;
    if ((t >= 256 && t < 260) || t == 324) o = 1.0f + softplusf(v);
    else if ((t >= 325 && t < 389) || (t >= 453 && t < 459)) o = sigf(v);
    sifa[t] = o;
  }
  if (t < 4){
    float p0 = sraw[459+t*3+0], p1 = sraw[459+t*3+1], p2 = sraw[459+t*3+2];
    float mx = fmaxf(p0, fmaxf(p1,p2));
    float e0 = expf(p0-mx), e1 = expf(p1-mx), e2 = expf(p2-mx);
    float s = e0+e1+e2;
    sifa[459+t*3+0]=e0/s; sifa[459+t*3+1]=e1/s; sifa[459+t*3+2]=e2/s;
  }
  __syncthreads();
  if (t < 471) ifa_ws[b*512 + t] = sifa[t];
  float f0 = sifa[453], f1 = sifa[454], f2 = sifa[455], f3 = sifa[456];
  float psi = (1.f - f0*rw_prev[(long)(b*4+0)*1024 + t])
            * (1.f - f1*rw_prev[(long)(b*4+1)*1024 + t])
            * (1.f - f2*rw_prev[(long)(b*4+2)*1024 + t])
            * (1.f - f3*rw_prev[(long)(b*4+3)*1024 + t]);
  float uu = usage_prev[b*1024+t], w = ww_prev[b*1024+t];
  float uval = (uu + w - uu*w) * psi;
  // order-preserving float->uint transform
  unsigned int ub = __float_as_uint(uval);
  unsigned int k32 = ub ^ (((int)ub >> 31) | 0x80000000u);
  unsigned long long key = ((unsigned long long)k32 << 32) | (unsigned int)t;
  // bitonic sort ascending (bit-identical to jnp.argsort stable order)
  for (int kk2 = 2; kk2 <= 1024; kk2 <<= 1){
    for (int j = kk2 >> 1; j > 0; j >>= 1){
      unsigned long long other;
      if (j >= 64){               // cross-wave: LDS route (uniform branch)
        keys[t] = key;
        __syncthreads();
        other = keys[t ^ j];
        __syncthreads();
      } else {                    // within-wave: shfl, no barrier
        other = __shfl_xor(key, j);
      }
      bool up = ((t & kk2) == 0);
      bool keepMin = (((t & j) == 0) == up);
      if (keepMin ? (other < key) : (other > key)) key = other;
    }
  }
  unsigned int hk = (unsigned int)(key >> 32);
  unsigned int ob = (hk & 0x80000000u) ? (hk ^ 0x80000000u) : ~hk;
  float su = __uint_as_float(ob);
  int oi = (int)(key & 1023u);
  // inclusive cumprod: wave shfl-scan + wave-total prefix
  float s = su;
  #pragma unroll
  for (int off = 1; off < 64; off <<= 1){
    float v = __shfl_up(s, off);
    if (lane >= off) s *= v;
  }
  if (lane == 63) wtot[wid] = s;
  __syncthreads();
  float wpre = 1.0f;
  for (int w2 = 0; w2 < wid; ++w2) wpre *= wtot[w2];
  float ex = __shfl_up(s, 1);
  if (lane == 0) ex = 1.0f;
  float cpe = ex * wpre;
  alloc_ws[b*1024 + oi] = (1.0f - su) * cpe;
}

// ---------------- K4: write-content scores — grid (16 at,16 b), block 512 (8 waves x 8 rows) ----------------
__global__ __launch_bounds__(512) void k_wscore(const float* __restrict__ mem_prev,
    const float* __restrict__ ifa_ws, float* __restrict__ wsc_ws){
  int at = blockIdx.x, b = blockIdx.y;
  int t = threadIdx.x, w = t >> 6, m = t & 63;
  const float* ifa = ifa_ws + b*512;
  float kwm = ifa[260+m], beta = ifa[324];
  float knsq = kwm*kwm;
  for (int o = 32; o > 0; o >>= 1) knsq += __shfl_xor(knsq, o);
  float kn = sqrtf(knsq);
  for (int rr = 0; rr < 8; ++rr){
    int a = at*64 + w*8 + rr;
    float v = mem_prev[((long)b*1024+a)*64+m];
    float d = v*kwm, sq = v*v;
    for (int o = 32; o > 0; o >>= 1){ d += __shfl_xor(d,o); sq += __shfl_xor(sq,o); }
    if (m == 0) wsc_ws[b*1024+a] = beta*d/(kn*sqrtf(sq)+1e-6f);
  }
}

// ---------------- K5: softmax(wsc) + ww + e=ww*rw — grid 16, block 1024 (wave reduce) ----------------
__global__ void k_cw_ww(const float* __restrict__ wsc_ws, const float* __restrict__ ifa_ws,
                        const float* __restrict__ alloc_ws, const float* __restrict__ rw_prev,
                        float* __restrict__ ww_ws, float* __restrict__ e_ws){
  __shared__ float wred[16]; __shared__ float wred2[16];
  int b = blockIdx.x, t = threadIdx.x, lane = t & 63, wid = t >> 6;
  const float* ifa = ifa_ws + b*512;
  float g_a = ifa[457], g_w = ifa[458];
  float sc = wsc_ws[b*1024+t];
  float m = sc;
  for (int o = 32; o > 0; o >>= 1) m = fmaxf(m, __shfl_xor(m, o));
  if (lane == 0) wred[wid] = m;
  __syncthreads();
  float mx = wred[0];
  #pragma unroll
  for (int i = 1; i < 16; ++i) mx = fmaxf(mx, wred[i]);
  float e = expf(sc - mx);
  float ssum = e;
  for (int o = 32; o > 0; o >>= 1) ssum += __shfl_xor(ssum, o);
  if (lane == 0) wred2[wid] = ssum;
  __syncthreads();
  float tot = 0.0f;
  #pragma unroll
  for (int i = 0; i < 16; ++i) tot += wred2[i];
  float cw = e / tot;
  float ww = g_w*(g_a*alloc_ws[b*1024+t] + (1.0f-g_a)*cw);
  ww_ws[b*1024+t] = ww;
  #pragma unroll
  for (int r = 0; r < 4; ++r)
    e_ws[(long)(b*4+r)*1024 + t] = ww * rw_prev[(long)(b*4+r)*1024 + t];
}

// ---------------- K6: MERGED score + linkfb — grid 256+4096 = 4352, block 256 ----------------
// bid < 256: score (norms + 4 read-key dots, 4 waves x 16 rows).
// bid >= 256: linkfb tile (band,ct,b) via affine decomposition.
__global__ __launch_bounds__(256) void k_slfb(const float* __restrict__ mem_prev,
    const float* __restrict__ ww_ws, const float* __restrict__ ifa_ws,
    float* __restrict__ mnorm_ws, float* __restrict__ rdot_ws,
    const float* __restrict__ link_prev, const float* __restrict__ rw_prev,
    const float* __restrict__ e_ws, const float* __restrict__ prec_prev,
    float* __restrict__ fwd_part, float* __restrict__ bwd_part){
  __shared__ float Lt[64][68];
  int bid = blockIdx.x, t = threadIdx.x;
  if (bid < 256){
    // ---- score ----
    int at = bid & 15, b = bid >> 4;
    int w = t >> 6, m = t & 63;
    const float* ifa = ifa_ws + b*512;
    float er = ifa[325+m], wv = ifa[389+m];
    float k0 = ifa[m], k1 = ifa[64+m], k2 = ifa[128+m], k3 = ifa[192+m];
    for (int rr = 0; rr < 16; ++rr){
      int a = at*64 + w*16 + rr;
      float ww = ww_ws[b*1024+a];
      float v = mem_prev[((long)b*1024+a)*64+m]*(1.0f - ww*er) + ww*wv;
      float sq = v*v, d0 = v*k0, d1 = v*k1, d2 = v*k2, d3 = v*k3;
      for (int o = 32; o > 0; o >>= 1){
        sq += __shfl_xor(sq,o); d0 += __shfl_xor(d0,o); d1 += __shfl_xor(d1,o);
        d2 += __shfl_xor(d2,o); d3 += __shfl_xor(d3,o);
      }
      if (m == 0){
        mnorm_ws[b*1024+a] = sqrtf(sq);
        rdot_ws[(long)(b*4+0)*1024+a] = d0; rdot_ws[(long)(b*4+1)*1024+a] = d1;
        rdot_ws[(long)(b*4+2)*1024+a] = d2; rdot_ws[(long)(b*4+3)*1024+a] = d3;
      }
    }
    return;
  }
  // ---- linkfb ----
  int lb = bid - 256;
  int band = lb & 15, ct = (lb >> 4) & 15, b = lb >> 8;
  int r = t >> 6, lane = t & 63;
  int ru = __builtin_amdgcn_readfirstlane(r);
  const float4* L4 = (const float4*)link_prev;
  #pragma unroll
  for (int q = 0; q < 4; ++q){
    int idx = t + 256*q;
    int row = idx >> 4, c4 = idx & 15;
    float4 v = L4[((long)b << 18) + (long)(band*64+row)*256 + ct*16 + c4];
    *(float4*)&Lt[row][c4*4] = v;
  }
  const float* aJ = rw_prev + (long)(b*4+ru)*1024 + ct*64;
  const float* eJ = e_ws    + (long)(b*4+ru)*1024 + ct*64;
  const float* aI = rw_prev + (long)(b*4+ru)*1024 + band*64;
  const float* eI = e_ws    + (long)(b*4+ru)*1024 + band*64;
  float pv = prec_prev[b*1024 + ct*64 + lane] * aJ[lane];
  float wvs = eI[lane];
  for (int o = 32; o > 0; o >>= 1){ pv += __shfl_xor(pv,o); wvs += __shfl_xor(wvs,o); }
  float wwi = ww_ws[b*1024 + band*64 + lane];
  float wwc = ww_ws[b*1024 + ct*64 + lane];
  float pc  = prec_prev[b*1024 + ct*64 + lane];
  __syncthreads();
  float A1 = 0.0f, A2 = 0.0f;
  for (int jc = 0; jc < 64; jc += 4){
    float4 Lv = *(const float4*)&Lt[lane][jc];
    A1 += Lv.x*aJ[jc] + Lv.y*aJ[jc+1] + Lv.z*aJ[jc+2] + Lv.w*aJ[jc+3];
    A2 += Lv.x*eJ[jc] + Lv.y*eJ[jc+1] + Lv.z*eJ[jc+2] + Lv.w*eJ[jc+3];
  }
  float facc = (1.0f - wwi)*A1 - A2 + wwi*pv;
  float B1 = 0.0f, B2 = 0.0f;
  for (int rowl = 0; rowl < 64; ++rowl){
    float Lv = Lt[rowl][lane];
    B1 += Lv * aI[rowl];
    B2 += Lv * eI[rowl];
  }
  float bacc = (1.0f - wwc)*B1 - B2 + pc*wvs;
  if (band == ct){
    float D = ((1.0f - 2.0f*wwi)*Lt[lane][lane] + wwi*pc)*aJ[lane];
    facc -= D;
    bacc -= D;
  }
  fwd_part[(long)ct*65536 + (long)(b*4+r)*1024 + band*64 + lane] = facc;
  bwd_part[(long)band*65536 + (long)(b*4+r)*1024 + ct*64 + lane] = bacc;
}

// ---------------- K8: read softmax + mix + rv (mem recomputed; fbred folded in) — grid (4,16), block 1024 ----------------
__global__ void k_read(const float* __restrict__ rdot_ws, const float* __restrict__ mnorm_ws,
                       const float* __restrict__ ifa_ws, const float* __restrict__ fwd_part,
                       const float* __restrict__ bwd_part, const float* __restrict__ mem_prev,
                       const float* __restrict__ ww_ws, float* __restrict__ rv_ws){
  __shared__ float red[1024]; __shared__ float wrs[1024]; __shared__ float wwsh[1024];
  __shared__ float par[1]; __shared__ float wred[16]; __shared__ float wred2[16];
  int r = blockIdx.x, b = blockIdx.y, t = threadIdx.x; // a = t
  int lane = t & 63, wid = t >> 6;
  const float* ifa = ifa_ws + b*512;
  long base = (long)(b*4+r)*1024 + t;
  float fsum = 0.0f, bsum = 0.0f;
  #pragma unroll
  for (int c = 0; c < 16; ++c){
    fsum += fwd_part[(long)c*65536 + base];
    bsum += bwd_part[(long)c*65536 + base];
  }
  if (t < 64){
    float v = ifa[r*64+t];
    float sq = v*v;
    for (int o = 32; o > 0; o >>= 1) sq += __shfl_xor(sq, o);
    if (t == 0) par[0] = sqrtf(sq);
  }
  wwsh[t] = ww_ws[b*1024+t];
  __syncthreads();
  float kn = par[0], beta = ifa[256 + r];
  float sc = beta * rdot_ws[base] / (kn*mnorm_ws[b*1024+t] + 1e-6f);
  float m = sc;
  for (int o = 32; o > 0; o >>= 1) m = fmaxf(m, __shfl_xor(m, o));
  if (lane == 0) wred[wid] = m;
  __syncthreads();
  float mx = wred[0];
  #pragma unroll
  for (int i = 1; i < 16; ++i) mx = fmaxf(mx, wred[i]);
  float e = expf(sc - mx);
  float s = e;
  for (int o = 32; o > 0; o >>= 1) s += __shfl_xor(s, o);
  if (lane == 0) wred2[wid] = s;
  __syncthreads();
  float tot = 0.0f;
  #pragma unroll
  for (int i = 0; i < 16; ++i) tot += wred2[i];
  float cr = e / tot;
  float p0 = ifa[459+3*r], p1 = ifa[460+3*r], p2 = ifa[461+3*r];
  wrs[t] = p0*bsum + p1*cr + p2*fsum;
  __syncthreads();
  int mm = t & 63, ch = t >> 6;
  float er = ifa[325+mm], wv = ifa[389+mm];
  float acc = 0;
  for (int q = 0; q < 64; ++q){
    int a = ch*64 + q;
    float w = wwsh[a];
    float v = mem_prev[((long)b*1024 + a)*64 + mm]*(1.0f - w*er) + w*wv;
    acc += wrs[a]*v;
  }
  red[ch*64 + mm] = acc;
  __syncthreads();
  if (t < 64){
    float s2 = 0;
    for (int c2 = 0; c2 < 16; ++c2) s2 += red[c2*64 + t];
    rv_ws[(b*4+r)*64 + t] = s2;
  }
}

// ---------------- K9: out = out_hidden + rv@W_rd + b_rd — grid 16, block 1024 (4-way K split) ----------------
__global__ void k_out(const float* __restrict__ outh_ws, const float* __restrict__ rv_ws,
                      const float* __restrict__ W_rd, const float* __restrict__ b_rd,
                      float* __restrict__ out){
  __shared__ float rvs[256]; __shared__ float part[4][256];
  int b = blockIdx.x, t = threadIdx.x;
  int o = t & 255, kq = t >> 8;
  if (t < 256) rvs[t] = rv_ws[b*256 + t];
  __syncthreads();
  float acc = 0.0f;
  for (int q = kq*64; q < kq*64 + 64; ++q) acc += rvs[q]*W_rd[(long)q*256 + o];
  part[kq][o] = acc;
  __syncthreads();
  if (t < 256)
    out[b*256+t] = outh_ws[b*256+t] + b_rd[t] + part[0][t] + part[1][t] + part[2][t] + part[3][t];
}

extern "C" void kernel_launch(void* const* d_in, const int* in_sizes, int n_in,
                              void* d_out, int out_size, void* d_ws, size_t ws_size,
                              hipStream_t stream){
  const float* x          = (const float*)d_in[0];
  const float* h_prev     = (const float*)d_in[1];
  const float* c_prev     = (const float*)d_in[2];
  const float* mem_prev   = (const float*)d_in[3];
  const float* rw_prev    = (const float*)d_in[4];
  const float* ww_prev    = (const float*)d_in[5];
  const float* usage_prev = (const float*)d_in[6];
  const float* prec_prev  = (const float*)d_in[7];
  const float* link_prev  = (const float*)d_in[8];
  const float* rv_prev    = (const float*)d_in[9];
  const float* Wx         = (const float*)d_in[10];
  const float* Wh         = (const float*)d_in[11];
  const float* b_lstm     = (const float*)d_in[12];
  const float* W_hid      = (const float*)d_in[13];
  const float* b_hid      = (const float*)d_in[14];
  const float* W_if       = (const float*)d_in[15];
  const float* b_if       = (const float*)d_in[16];
  const float* W_rd       = (const float*)d_in[17];
  const float* b_rd       = (const float*)d_in[18];
  float* out = (float*)d_out;

  // ws layout (floats), total 3178496 = 12.7 MB (unchanged offsets)
  float* ws = (float*)d_ws;
  float* h_ws     = ws + 0;          // 8192
  float* ifr_ws   = ws + 8192;       // 8192 (unused now)
  float* ifa_ws   = ws + 16384;      // 8192
  float* outh_ws  = ws + 24576;      // 4096
  float* alloc_ws = ws + 28672;      // 16384
  float* ww_ws    = ws + 45056;      // 16384
  float* mnorm_ws = ws + 61440;      // 16384
  float* wsc_ws   = ws + 77824;      // 16384
  float* rv_ws    = ws + 94208;      // 4096
  float* fwd_ws   = ws + 98304;      // 65536 (unused)
  float* bwd_ws   = ws + 163840;     // 65536 (unused)
  float* rdot_ws  = ws + 229376;     // 65536
  float* e_ws     = ws + 294912;     // 65536
  float* zpart    = ws + 360448;     // 524288
  float* ifpart   = ws + 884736;     // 196608
  float* fwd_part = ws + 1081344;    // 1048576 (16 ct x 65536)
  float* bwd_part = ws + 2129920;    // 1048576 (16 band x 65536)
  (void)ifr_ws; (void)fwd_ws; (void)bwd_ws;

  k_lstm_part<<<dim3(8,16),256,0,stream>>>(x, rv_prev, h_prev, Wx, Wh, zpart);
  k_lstm_fin<<<dim3(4,16),128,0,stream>>>(zpart, b_lstm, c_prev, h_ws);
  k_iface_part<<<dim3(3,16),256,0,stream>>>(h_ws, W_if, W_hid, ifpart);
  k_actfa<<<16,1024,0,stream>>>(ifpart, b_if, b_hid, rw_prev, ww_prev, usage_prev,
                                outh_ws, ifa_ws, alloc_ws);
  k_wscore<<<dim3(16,16),512,0,stream>>>(mem_prev, ifa_ws, wsc_ws);
  k_cw_ww<<<16,1024,0,stream>>>(wsc_ws, ifa_ws, alloc_ws, rw_prev, ww_ws, e_ws);
  k_slfb<<<4352,256,0,stream>>>(mem_prev, ww_ws, ifa_ws, mnorm_ws, rdot_ws,
                                link_prev, rw_prev, e_ws, prec_prev, fwd_part, bwd_part);
  k_read<<<dim3(4,16),1024,0,stream>>>(rdot_ws, mnorm_ws, ifa_ws, fwd_part, bwd_part,
                                       mem_prev, ww_ws, rv_ws);
  k_out<<<16,1024,0,stream>>>(outh_ws, rv_ws, W_rd, b_rd, out);
}

// Round 6
// 226.214 us; speedup vs baseline: 1.1632x; 1.0143x over previous
//
#include <hip/hip_runtime.h>
#include <math.h>

// (B,I,H,O,A,M,R) = (16,256,512,256,1024,64,4), IF=471. All fp32.

__device__ __forceinline__ float sigf(float x){ return 1.0f/(1.0f+expf(-x)); }
__device__ __forceinline__ float softplusf(float x){ return fmaxf(x,0.0f)+log1pf(expf(-fabsf(x))); }

// ---------------- K1a: LSTM partial GEMM — grid (16 ct,16 kt), block 128 ----------------
// inp transposed [kk][bb] (pad 20: 16B-aligned rows) -> 4x ds_read_b128 broadcast per kk
// instead of 16x ds_read_b32. Same accumulation order -> bitwise identical.
__global__ __launch_bounds__(128) void k_lstm_part(const float* __restrict__ x,
    const float* __restrict__ rv, const float* __restrict__ hp,
    const float* __restrict__ Wx, const float* __restrict__ Wh,
    float* __restrict__ zpart){
  __shared__ float inp[64][20];
  int ct = blockIdx.x, kt = blockIdx.y, t = threadIdx.x;
  #pragma unroll
  for (int q = 0; q < 8; ++q){
    int i = t + 128*q;
    int bb = i >> 6, kk = i & 63;
    int k = kt*64 + kk;
    float v = (k < 256) ? x[bb*256+k] : (k < 512) ? rv[bb*256 + k-256] : hp[bb*512 + k-512];
    inp[kk][bb] = v;
  }
  __syncthreads();
  int col = ct*128 + t;
  float acc[16];
  #pragma unroll
  for (int bb = 0; bb < 16; ++bb) acc[bb] = 0.0f;
  for (int kk = 0; kk < 64; ++kk){
    int k = kt*64 + kk;
    float w = (k < 512) ? Wx[(long)k*2048 + col] : Wh[(long)(k-512)*2048 + col];
    float4 v0 = *(const float4*)&inp[kk][0];
    float4 v1 = *(const float4*)&inp[kk][4];
    float4 v2 = *(const float4*)&inp[kk][8];
    float4 v3 = *(const float4*)&inp[kk][12];
    acc[0]  += v0.x*w; acc[1]  += v0.y*w; acc[2]  += v0.z*w; acc[3]  += v0.w*w;
    acc[4]  += v1.x*w; acc[5]  += v1.y*w; acc[6]  += v1.z*w; acc[7]  += v1.w*w;
    acc[8]  += v2.x*w; acc[9]  += v2.y*w; acc[10] += v2.z*w; acc[11] += v2.w*w;
    acc[12] += v3.x*w; acc[13] += v3.y*w; acc[14] += v3.z*w; acc[15] += v3.w*w;
  }
  #pragma unroll
  for (int bb = 0; bb < 16; ++bb)
    zpart[((long)kt*16 + bb)*2048 + col] = acc[bb];
}

// ---------------- K1b: LSTM finish — grid (4 jt, 16 b), block 128 ----------------
__global__ void k_lstm_fin(const float* __restrict__ zpart, const float* __restrict__ bl,
                           const float* __restrict__ cp, float* __restrict__ h_ws){
  int jt = blockIdx.x, b = blockIdx.y, j = jt*128 + threadIdx.x;
  float zi = bl[j], zf = bl[512+j], zg = bl[1024+j], zo = bl[1536+j];
  for (int kt = 0; kt < 16; ++kt){
    const float* zp = zpart + ((long)kt*16 + b)*2048;
    zi += zp[j]; zf += zp[512+j]; zg += zp[1024+j]; zo += zp[1536+j];
  }
  float c = sigf(zf)*cp[b*512+j] + sigf(zi)*tanhf(zg);
  h_ws[b*512+j] = sigf(zo)*tanhf(c);
}

// ---------------- K2a: iface/out_hidden partial GEMM — grid (6 ct,16 kt), block 128 ----------------
__global__ __launch_bounds__(128) void k_iface_part(const float* __restrict__ h_ws,
    const float* __restrict__ W_if, const float* __restrict__ W_hid,
    float* __restrict__ ifpart){
  __shared__ float hh[32][20];
  int ct = blockIdx.x, kt = blockIdx.y, t = threadIdx.x;
  #pragma unroll
  for (int q = 0; q < 4; ++q){
    int i = t + 128*q;
    int bb = i >> 5, kk = i & 31;
    hh[kk][bb] = h_ws[bb*512 + kt*32 + kk];
  }
  __syncthreads();
  int col = ct*128 + t;
  float acc[16];
  #pragma unroll
  for (int bb = 0; bb < 16; ++bb) acc[bb] = 0.0f;
  if (col < 727){
    for (int kk = 0; kk < 32; ++kk){
      int k = kt*32 + kk;
      float w = (col < 471) ? W_if[(long)k*471 + col] : W_hid[(long)k*256 + (col-471)];
      float4 v0 = *(const float4*)&hh[kk][0];
      float4 v1 = *(const float4*)&hh[kk][4];
      float4 v2 = *(const float4*)&hh[kk][8];
      float4 v3 = *(const float4*)&hh[kk][12];
      acc[0]  += v0.x*w; acc[1]  += v0.y*w; acc[2]  += v0.z*w; acc[3]  += v0.w*w;
      acc[4]  += v1.x*w; acc[5]  += v1.y*w; acc[6]  += v1.z*w; acc[7]  += v1.w*w;
      acc[8]  += v2.x*w; acc[9]  += v2.y*w; acc[10] += v2.z*w; acc[11] += v2.w*w;
      acc[12] += v3.x*w; acc[13] += v3.y*w; acc[14] += v3.z*w; acc[15] += v3.w*w;
    }
    #pragma unroll
    for (int bb = 0; bb < 16; ++bb)
      ifpart[((long)kt*16 + bb)*768 + col] = acc[bb];
  }
}

// ---------------- K3: FUSED iface-finish + activations + psi + usage + register BITONIC + alloc ----------------
// grid 16, block 1024.
// iface layout: k_r[0,256) beta_r[256,260) k_w[260,324) beta_w[324] erase[325,389)
//               write_v[389,453) free[453,457) g_a[457] g_w[458] pi[459,471)
__global__ __launch_bounds__(1024) void k_actfa(const float* __restrict__ ifpart,
                            const float* __restrict__ b_if, const float* __restrict__ b_hid,
                            const float* __restrict__ rw_prev,
                            const float* __restrict__ ww_prev, const float* __restrict__ usage_prev,
                            float* __restrict__ outh_ws,
                            float* __restrict__ ifa_ws, float* __restrict__ alloc_ws){
  __shared__ float sraw[480];
  __shared__ float sifa[480];
  __shared__ unsigned long long keys[1024];
  __shared__ float wtot[16];
  int b = blockIdx.x, t = threadIdx.x;
  int lane = t & 63, wid = t >> 6;
  if (t < 727){
    float s = (t < 471) ? b_if[t] : b_hid[t-471];
    #pragma unroll
    for (int kt = 0; kt < 16; ++kt) s += ifpart[((long)kt*16 + b)*768 + t];
    if (t < 471) sraw[t] = s;
    else         outh_ws[b*256 + (t-471)] = s;
  }
  __syncthreads();
  if (t < 459){
    float v = sraw[t], o = v;
    if ((t >= 256 && t < 260) || t == 324) o = 1.0f + softplusf(v);
    else if ((t >= 325 && t < 389) || (t >= 453 && t < 459)) o = sigf(v);
    sifa[t] = o;
  }
  if (t < 4){
    float p0 = sraw[459+t*3+0], p1 = sraw[459+t*3+1], p2 = sraw[459+t*3+2];
    float mx = fmaxf(p0, fmaxf(p1,p2));
    float e0 = expf(p0-mx), e1 = expf(p1-mx), e2 = expf(p2-mx);
    float s = e0+e1+e2;
    sifa[459+t*3+0]=e0/s; sifa[459+t*3+1]=e1/s; sifa[459+t*3+2]=e2/s;
  }
  __syncthreads();
  if (t < 471) ifa_ws[b*512 + t] = sifa[t];
  float f0 = sifa[453], f1 = sifa[454], f2 = sifa[455], f3 = sifa[456];
  float psi = (1.f - f0*rw_prev[(long)(b*4+0)*1024 + t])
            * (1.f - f1*rw_prev[(long)(b*4+1)*1024 + t])
            * (1.f - f2*rw_prev[(long)(b*4+2)*1024 + t])
            * (1.f - f3*rw_prev[(long)(b*4+3)*1024 + t]);
  float uu = usage_prev[b*1024+t], w = ww_prev[b*1024+t];
  float uval = (uu + w - uu*w) * psi;
  unsigned int ub = __float_as_uint(uval);
  unsigned int k32 = ub ^ (((int)ub >> 31) | 0x80000000u);
  unsigned long long key = ((unsigned long long)k32 << 32) | (unsigned int)t;
  for (int kk2 = 2; kk2 <= 1024; kk2 <<= 1){
    for (int j = kk2 >> 1; j > 0; j >>= 1){
      unsigned long long other;
      if (j >= 64){
        keys[t] = key;
        __syncthreads();
        other = keys[t ^ j];
        __syncthreads();
      } else {
        other = __shfl_xor(key, j);
      }
      bool up = ((t & kk2) == 0);
      bool keepMin = (((t & j) == 0) == up);
      if (keepMin ? (other < key) : (other > key)) key = other;
    }
  }
  unsigned int hk = (unsigned int)(key >> 32);
  unsigned int ob = (hk & 0x80000000u) ? (hk ^ 0x80000000u) : ~hk;
  float su = __uint_as_float(ob);
  int oi = (int)(key & 1023u);
  float s = su;
  #pragma unroll
  for (int off = 1; off < 64; off <<= 1){
    float v = __shfl_up(s, off);
    if (lane >= off) s *= v;
  }
  if (lane == 63) wtot[wid] = s;
  __syncthreads();
  float wpre = 1.0f;
  for (int w2 = 0; w2 < wid; ++w2) wpre *= wtot[w2];
  float ex = __shfl_up(s, 1);
  if (lane == 0) ex = 1.0f;
  float cpe = ex * wpre;
  alloc_ws[b*1024 + oi] = (1.0f - su) * cpe;
}

// ---------------- K4: write-content scores — grid (16 at,16 b), block 512 (8 waves x 8 rows) ----------------
__global__ __launch_bounds__(512) void k_wscore(const float* __restrict__ mem_prev,
    const float* __restrict__ ifa_ws, float* __restrict__ wsc_ws){
  int at = blockIdx.x, b = blockIdx.y;
  int t = threadIdx.x, w = t >> 6, m = t & 63;
  const float* ifa = ifa_ws + b*512;
  float kwm = ifa[260+m], beta = ifa[324];
  float knsq = kwm*kwm;
  for (int o = 32; o > 0; o >>= 1) knsq += __shfl_xor(knsq, o);
  float kn = sqrtf(knsq);
  for (int rr = 0; rr < 8; ++rr){
    int a = at*64 + w*8 + rr;
    float v = mem_prev[((long)b*1024+a)*64+m];
    float d = v*kwm, sq = v*v;
    for (int o = 32; o > 0; o >>= 1){ d += __shfl_xor(d,o); sq += __shfl_xor(sq,o); }
    if (m == 0) wsc_ws[b*1024+a] = beta*d/(kn*sqrtf(sq)+1e-6f);
  }
}

// ---------------- K5: softmax(wsc) + ww + e=ww*rw — grid 16, block 1024 (wave reduce) ----------------
__global__ void k_cw_ww(const float* __restrict__ wsc_ws, const float* __restrict__ ifa_ws,
                        const float* __restrict__ alloc_ws, const float* __restrict__ rw_prev,
                        float* __restrict__ ww_ws, float* __restrict__ e_ws){
  __shared__ float wred[16]; __shared__ float wred2[16];
  int b = blockIdx.x, t = threadIdx.x, lane = t & 63, wid = t >> 6;
  const float* ifa = ifa_ws + b*512;
  float g_a = ifa[457], g_w = ifa[458];
  float sc = wsc_ws[b*1024+t];
  float m = sc;
  for (int o = 32; o > 0; o >>= 1) m = fmaxf(m, __shfl_xor(m, o));
  if (lane == 0) wred[wid] = m;
  __syncthreads();
  float mx = wred[0];
  #pragma unroll
  for (int i = 1; i < 16; ++i) mx = fmaxf(mx, wred[i]);
  float e = expf(sc - mx);
  float ssum = e;
  for (int o = 32; o > 0; o >>= 1) ssum += __shfl_xor(ssum, o);
  if (lane == 0) wred2[wid] = ssum;
  __syncthreads();
  float tot = 0.0f;
  #pragma unroll
  for (int i = 0; i < 16; ++i) tot += wred2[i];
  float cw = e / tot;
  float ww = g_w*(g_a*alloc_ws[b*1024+t] + (1.0f-g_a)*cw);
  ww_ws[b*1024+t] = ww;
  #pragma unroll
  for (int r = 0; r < 4; ++r)
    e_ws[(long)(b*4+r)*1024 + t] = ww * rw_prev[(long)(b*4+r)*1024 + t];
}

// ---------------- K6: MERGED score + linkfb — grid 256+4096 = 4352, block 256 ----------------
__global__ __launch_bounds__(256) void k_slfb(const float* __restrict__ mem_prev,
    const float* __restrict__ ww_ws, const float* __restrict__ ifa_ws,
    float* __restrict__ mnorm_ws, float* __restrict__ rdot_ws,
    const float* __restrict__ link_prev, const float* __restrict__ rw_prev,
    const float* __restrict__ e_ws, const float* __restrict__ prec_prev,
    float* __restrict__ fwd_part, float* __restrict__ bwd_part){
  __shared__ float Lt[64][68];
  int bid = blockIdx.x, t = threadIdx.x;
  if (bid < 256){
    int at = bid & 15, b = bid >> 4;
    int w = t >> 6, m = t & 63;
    const float* ifa = ifa_ws + b*512;
    float er = ifa[325+m], wv = ifa[389+m];
    float k0 = ifa[m], k1 = ifa[64+m], k2 = ifa[128+m], k3 = ifa[192+m];
    for (int rr = 0; rr < 16; ++rr){
      int a = at*64 + w*16 + rr;
      float ww = ww_ws[b*1024+a];
      float v = mem_prev[((long)b*1024+a)*64+m]*(1.0f - ww*er) + ww*wv;
      float sq = v*v, d0 = v*k0, d1 = v*k1, d2 = v*k2, d3 = v*k3;
      for (int o = 32; o > 0; o >>= 1){
        sq += __shfl_xor(sq,o); d0 += __shfl_xor(d0,o); d1 += __shfl_xor(d1,o);
        d2 += __shfl_xor(d2,o); d3 += __shfl_xor(d3,o);
      }
      if (m == 0){
        mnorm_ws[b*1024+a] = sqrtf(sq);
        rdot_ws[(long)(b*4+0)*1024+a] = d0; rdot_ws[(long)(b*4+1)*1024+a] = d1;
        rdot_ws[(long)(b*4+2)*1024+a] = d2; rdot_ws[(long)(b*4+3)*1024+a] = d3;
      }
    }
    return;
  }
  int lb = bid - 256;
  int band = lb & 15, ct = (lb >> 4) & 15, b = lb >> 8;
  int r = t >> 6, lane = t & 63;
  int ru = __builtin_amdgcn_readfirstlane(r);
  const float4* L4 = (const float4*)link_prev;
  #pragma unroll
  for (int q = 0; q < 4; ++q){
    int idx = t + 256*q;
    int row = idx >> 4, c4 = idx & 15;
    float4 v = L4[((long)b << 18) + (long)(band*64+row)*256 + ct*16 + c4];
    *(float4*)&Lt[row][c4*4] = v;
  }
  const float* aJ = rw_prev + (long)(b*4+ru)*1024 + ct*64;
  const float* eJ = e_ws    + (long)(b*4+ru)*1024 + ct*64;
  const float* aI = rw_prev + (long)(b*4+ru)*1024 + band*64;
  const float* eI = e_ws    + (long)(b*4+ru)*1024 + band*64;
  float pv = prec_prev[b*1024 + ct*64 + lane] * aJ[lane];
  float wvs = eI[lane];
  for (int o = 32; o > 0; o >>= 1){ pv += __shfl_xor(pv,o); wvs += __shfl_xor(wvs,o); }
  float wwi = ww_ws[b*1024 + band*64 + lane];
  float wwc = ww_ws[b*1024 + ct*64 + lane];
  float pc  = prec_prev[b*1024 + ct*64 + lane];
  __syncthreads();
  float A1 = 0.0f, A2 = 0.0f;
  for (int jc = 0; jc < 64; jc += 4){
    float4 Lv = *(const float4*)&Lt[lane][jc];
    A1 += Lv.x*aJ[jc] + Lv.y*aJ[jc+1] + Lv.z*aJ[jc+2] + Lv.w*aJ[jc+3];
    A2 += Lv.x*eJ[jc] + Lv.y*eJ[jc+1] + Lv.z*eJ[jc+2] + Lv.w*eJ[jc+3];
  }
  float facc = (1.0f - wwi)*A1 - A2 + wwi*pv;
  float B1 = 0.0f, B2 = 0.0f;
  for (int rowl = 0; rowl < 64; ++rowl){
    float Lv = Lt[rowl][lane];
    B1 += Lv * aI[rowl];
    B2 += Lv * eI[rowl];
  }
  float bacc = (1.0f - wwc)*B1 - B2 + pc*wvs;
  if (band == ct){
    float D = ((1.0f - 2.0f*wwi)*Lt[lane][lane] + wwi*pc)*aJ[lane];
    facc -= D;
    bacc -= D;
  }
  fwd_part[(long)ct*65536 + (long)(b*4+r)*1024 + band*64 + lane] = facc;
  bwd_part[(long)band*65536 + (long)(b*4+r)*1024 + ct*64 + lane] = bacc;
}

// ---------------- K8: read softmax + mix + rv — grid (4,16), block 1024 ----------------
__global__ void k_read(const float* __restrict__ rdot_ws, const float* __restrict__ mnorm_ws,
                       const float* __restrict__ ifa_ws, const float* __restrict__ fwd_part,
                       const float* __restrict__ bwd_part, const float* __restrict__ mem_prev,
                       const float* __restrict__ ww_ws, float* __restrict__ rv_ws){
  __shared__ __align__(16) float red[1024];
  __shared__ __align__(16) float wrs[1024];
  __shared__ __align__(16) float wwsh[1024];
  __shared__ float par[1]; __shared__ float wred[16]; __shared__ float wred2[16];
  int r = blockIdx.x, b = blockIdx.y, t = threadIdx.x; // a = t
  int lane = t & 63, wid = t >> 6;
  const float* ifa = ifa_ws + b*512;
  long base = (long)(b*4+r)*1024 + t;
  float fsum = 0.0f, bsum = 0.0f;
  #pragma unroll
  for (int c = 0; c < 16; ++c){
    fsum += fwd_part[(long)c*65536 + base];
    bsum += bwd_part[(long)c*65536 + base];
  }
  if (t < 64){
    float v = ifa[r*64+t];
    float sq = v*v;
    for (int o = 32; o > 0; o >>= 1) sq += __shfl_xor(sq, o);
    if (t == 0) par[0] = sqrtf(sq);
  }
  wwsh[t] = ww_ws[b*1024+t];
  __syncthreads();
  float kn = par[0], beta = ifa[256 + r];
  float sc = beta * rdot_ws[base] / (kn*mnorm_ws[b*1024+t] + 1e-6f);
  float m = sc;
  for (int o = 32; o > 0; o >>= 1) m = fmaxf(m, __shfl_xor(m, o));
  if (lane == 0) wred[wid] = m;
  __syncthreads();
  float mx = wred[0];
  #pragma unroll
  for (int i = 1; i < 16; ++i) mx = fmaxf(mx, wred[i]);
  float e = expf(sc - mx);
  float s = e;
  for (int o = 32; o > 0; o >>= 1) s += __shfl_xor(s, o);
  if (lane == 0) wred2[wid] = s;
  __syncthreads();
  float tot = 0.0f;
  #pragma unroll
  for (int i = 0; i < 16; ++i) tot += wred2[i];
  float cr = e / tot;
  float p0 = ifa[459+3*r], p1 = ifa[460+3*r], p2 = ifa[461+3*r];
  wrs[t] = p0*bsum + p1*cr + p2*fsum;
  __syncthreads();
  int mm = t & 63, ch = t >> 6;
  float er = ifa[325+mm], wv = ifa[389+mm];
  const float* memb = mem_prev + (long)b*65536 + mm;
  float acc = 0;
  for (int q = 0; q < 64; q += 4){
    int a = ch*64 + q;
    float4 w4 = *(const float4*)&wwsh[a];
    float4 r4 = *(const float4*)&wrs[a];
    float v0 = memb[(long)(a+0)*64]*(1.0f - w4.x*er) + w4.x*wv;
    float v1 = memb[(long)(a+1)*64]*(1.0f - w4.y*er) + w4.y*wv;
    float v2 = memb[(long)(a+2)*64]*(1.0f - w4.z*er) + w4.z*wv;
    float v3 = memb[(long)(a+3)*64]*(1.0f - w4.w*er) + w4.w*wv;
    acc += r4.x*v0; acc += r4.y*v1; acc += r4.z*v2; acc += r4.w*v3;
  }
  red[ch*64 + mm] = acc;
  __syncthreads();
  if (t < 64){
    float s2 = 0;
    for (int c2 = 0; c2 < 16; ++c2) s2 += red[c2*64 + t];
    rv_ws[(b*4+r)*64 + t] = s2;
  }
}

// ---------------- K9: out = out_hidden + rv@W_rd + b_rd — grid 16, block 1024 (4-way K split) ----------------
__global__ void k_out(const float* __restrict__ outh_ws, const float* __restrict__ rv_ws,
                      const float* __restrict__ W_rd, const float* __restrict__ b_rd,
                      float* __restrict__ out){
  __shared__ float rvs[256]; __shared__ float part[4][256];
  int b = blockIdx.x, t = threadIdx.x;
  int o = t & 255, kq = t >> 8;
  if (t < 256) rvs[t] = rv_ws[b*256 + t];
  __syncthreads();
  float acc = 0.0f;
  for (int q = kq*64; q < kq*64 + 64; ++q) acc += rvs[q]*W_rd[(long)q*256 + o];
  part[kq][o] = acc;
  __syncthreads();
  if (t < 256)
    out[b*256+t] = outh_ws[b*256+t] + b_rd[t] + part[0][t] + part[1][t] + part[2][t] + part[3][t];
}

extern "C" void kernel_launch(void* const* d_in, const int* in_sizes, int n_in,
                              void* d_out, int out_size, void* d_ws, size_t ws_size,
                              hipStream_t stream){
  const float* x          = (const float*)d_in[0];
  const float* h_prev     = (const float*)d_in[1];
  const float* c_prev     = (const float*)d_in[2];
  const float* mem_prev   = (const float*)d_in[3];
  const float* rw_prev    = (const float*)d_in[4];
  const float* ww_prev    = (const float*)d_in[5];
  const float* usage_prev = (const float*)d_in[6];
  const float* prec_prev  = (const float*)d_in[7];
  const float* link_prev  = (const float*)d_in[8];
  const float* rv_prev    = (const float*)d_in[9];
  const float* Wx         = (const float*)d_in[10];
  const float* Wh         = (const float*)d_in[11];
  const float* b_lstm     = (const float*)d_in[12];
  const float* W_hid      = (const float*)d_in[13];
  const float* b_hid      = (const float*)d_in[14];
  const float* W_if       = (const float*)d_in[15];
  const float* b_if       = (const float*)d_in[16];
  const float* W_rd       = (const float*)d_in[17];
  const float* b_rd       = (const float*)d_in[18];
  float* out = (float*)d_out;

  // ws layout (floats), total 3178496 = 12.7 MB (unchanged offsets)
  float* ws = (float*)d_ws;
  float* h_ws     = ws + 0;          // 8192
  float* ifr_ws   = ws + 8192;       // 8192 (unused)
  float* ifa_ws   = ws + 16384;      // 8192
  float* outh_ws  = ws + 24576;      // 4096
  float* alloc_ws = ws + 28672;      // 16384
  float* ww_ws    = ws + 45056;      // 16384
  float* mnorm_ws = ws + 61440;      // 16384
  float* wsc_ws   = ws + 77824;      // 16384
  float* rv_ws    = ws + 94208;      // 4096
  float* fwd_ws   = ws + 98304;      // 65536 (unused)
  float* bwd_ws   = ws + 163840;     // 65536 (unused)
  float* rdot_ws  = ws + 229376;     // 65536
  float* e_ws     = ws + 294912;     // 65536
  float* zpart    = ws + 360448;     // 524288
  float* ifpart   = ws + 884736;     // 196608
  float* fwd_part = ws + 1081344;    // 1048576 (16 ct x 65536)
  float* bwd_part = ws + 2129920;    // 1048576 (16 band x 65536)
  (void)ifr_ws; (void)fwd_ws; (void)bwd_ws;

  k_lstm_part<<<dim3(16,16),128,0,stream>>>(x, rv_prev, h_prev, Wx, Wh, zpart);
  k_lstm_fin<<<dim3(4,16),128,0,stream>>>(zpart, b_lstm, c_prev, h_ws);
  k_iface_part<<<dim3(6,16),128,0,stream>>>(h_ws, W_if, W_hid, ifpart);
  k_actfa<<<16,1024,0,stream>>>(ifpart, b_if, b_hid, rw_prev, ww_prev, usage_prev,
                                outh_ws, ifa_ws, alloc_ws);
  k_wscore<<<dim3(16,16),512,0,stream>>>(mem_prev, ifa_ws, wsc_ws);
  k_cw_ww<<<16,1024,0,stream>>>(wsc_ws, ifa_ws, alloc_ws, rw_prev, ww_ws, e_ws);
  k_slfb<<<4352,256,0,stream>>>(mem_prev, ww_ws, ifa_ws, mnorm_ws, rdot_ws,
                                link_prev, rw_prev, e_ws, prec_prev, fwd_part, bwd_part);
  k_read<<<dim3(4,16),1024,0,stream>>>(rdot_ws, mnorm_ws, ifa_ws, fwd_part, bwd_part,
                                       mem_prev, ww_ws, rv_ws);
  k_out<<<16,1024,0,stream>>>(outh_ws, rv_ws, W_rd, b_rd, out);
}

// Round 7
// 218.164 us; speedup vs baseline: 1.2061x; 1.0369x over previous
//
#include <hip/hip_runtime.h>
#include <math.h>

// (B,I,H,O,A,M,R) = (16,256,512,256,1024,64,4), IF=471. All fp32.

__device__ __forceinline__ float sigf(float x){ return 1.0f/(1.0f+expf(-x)); }
__device__ __forceinline__ float softplusf(float x){ return fmaxf(x,0.0f)+log1pf(expf(-fabsf(x))); }

// ---------------- K1a: LSTM partial GEMM — grid (16 ct, 32 kt), block 128, K=32/tile ----------------
// 512 blocks = 2 blocks/CU (vs 256 = 1) -> 2x resident waves for latency hiding.
// unroll 4: 4 weight loads in flight. Accumulation within tile stays ascending-k.
__global__ __launch_bounds__(128) void k_lstm_part(const float* __restrict__ x,
    const float* __restrict__ rv, const float* __restrict__ hp,
    const float* __restrict__ Wx, const float* __restrict__ Wh,
    float* __restrict__ zpart){
  __shared__ float inp[32][20];
  int ct = blockIdx.x, kt = blockIdx.y, t = threadIdx.x;
  #pragma unroll
  for (int q = 0; q < 4; ++q){
    int i = t + 128*q;
    int bb = i >> 5, kk = i & 31;
    int k = kt*32 + kk;
    float v = (k < 256) ? x[bb*256+k] : (k < 512) ? rv[bb*256 + k-256] : hp[bb*512 + k-512];
    inp[kk][bb] = v;
  }
  __syncthreads();
  int col = ct*128 + t;
  float acc[16];
  #pragma unroll
  for (int bb = 0; bb < 16; ++bb) acc[bb] = 0.0f;
  #pragma unroll 4
  for (int kk = 0; kk < 32; ++kk){
    int k = kt*32 + kk;
    float w = (k < 512) ? Wx[(long)k*2048 + col] : Wh[(long)(k-512)*2048 + col];
    float4 v0 = *(const float4*)&inp[kk][0];
    float4 v1 = *(const float4*)&inp[kk][4];
    float4 v2 = *(const float4*)&inp[kk][8];
    float4 v3 = *(const float4*)&inp[kk][12];
    acc[0]  += v0.x*w; acc[1]  += v0.y*w; acc[2]  += v0.z*w; acc[3]  += v0.w*w;
    acc[4]  += v1.x*w; acc[5]  += v1.y*w; acc[6]  += v1.z*w; acc[7]  += v1.w*w;
    acc[8]  += v2.x*w; acc[9]  += v2.y*w; acc[10] += v2.z*w; acc[11] += v2.w*w;
    acc[12] += v3.x*w; acc[13] += v3.y*w; acc[14] += v3.z*w; acc[15] += v3.w*w;
  }
  #pragma unroll
  for (int bb = 0; bb < 16; ++bb)
    zpart[((long)kt*16 + bb)*2048 + col] = acc[bb];
}

// ---------------- K1b: LSTM finish — grid (4 jt, 16 b), block 128, 32 partials ----------------
__global__ void k_lstm_fin(const float* __restrict__ zpart, const float* __restrict__ bl,
                           const float* __restrict__ cp, float* __restrict__ h_ws){
  int jt = blockIdx.x, b = blockIdx.y, j = jt*128 + threadIdx.x;
  float zi = bl[j], zf = bl[512+j], zg = bl[1024+j], zo = bl[1536+j];
  #pragma unroll 8
  for (int kt = 0; kt < 32; ++kt){
    const float* zp = zpart + ((long)kt*16 + b)*2048;
    zi += zp[j]; zf += zp[512+j]; zg += zp[1024+j]; zo += zp[1536+j];
  }
  float c = sigf(zf)*cp[b*512+j] + sigf(zi)*tanhf(zg);
  h_ws[b*512+j] = sigf(zo)*tanhf(c);
}

// ---------------- K2a: iface/out_hidden partial GEMM — grid (6 ct, 32 kt), block 128, K=16/tile ----------------
__global__ __launch_bounds__(128) void k_iface_part(const float* __restrict__ h_ws,
    const float* __restrict__ W_if, const float* __restrict__ W_hid,
    float* __restrict__ ifpart){
  __shared__ float hh[16][20];
  int ct = blockIdx.x, kt = blockIdx.y, t = threadIdx.x;
  #pragma unroll
  for (int q = 0; q < 2; ++q){
    int i = t + 128*q;
    int bb = i >> 4, kk = i & 15;
    hh[kk][bb] = h_ws[bb*512 + kt*16 + kk];
  }
  __syncthreads();
  int col = ct*128 + t;
  float acc[16];
  #pragma unroll
  for (int bb = 0; bb < 16; ++bb) acc[bb] = 0.0f;
  if (col < 727){
    #pragma unroll 4
    for (int kk = 0; kk < 16; ++kk){
      int k = kt*16 + kk;
      float w = (col < 471) ? W_if[(long)k*471 + col] : W_hid[(long)k*256 + (col-471)];
      float4 v0 = *(const float4*)&hh[kk][0];
      float4 v1 = *(const float4*)&hh[kk][4];
      float4 v2 = *(const float4*)&hh[kk][8];
      float4 v3 = *(const float4*)&hh[kk][12];
      acc[0]  += v0.x*w; acc[1]  += v0.y*w; acc[2]  += v0.z*w; acc[3]  += v0.w*w;
      acc[4]  += v1.x*w; acc[5]  += v1.y*w; acc[6]  += v1.z*w; acc[7]  += v1.w*w;
      acc[8]  += v2.x*w; acc[9]  += v2.y*w; acc[10] += v2.z*w; acc[11] += v2.w*w;
      acc[12] += v3.x*w; acc[13] += v3.y*w; acc[14] += v3.z*w; acc[15] += v3.w*w;
    }
    #pragma unroll
    for (int bb = 0; bb < 16; ++bb)
      ifpart[((long)kt*16 + bb)*768 + col] = acc[bb];
  }
}

// ---------------- K3: FUSED iface-finish + activations + psi + usage + register BITONIC + alloc ----------------
// grid 16, block 1024. 32 K-partials now.
// iface layout: k_r[0,256) beta_r[256,260) k_w[260,324) beta_w[324] erase[325,389)
//               write_v[389,453) free[453,457) g_a[457] g_w[458] pi[459,471)
__global__ __launch_bounds__(1024) void k_actfa(const float* __restrict__ ifpart,
                            const float* __restrict__ b_if, const float* __restrict__ b_hid,
                            const float* __restrict__ rw_prev,
                            const float* __restrict__ ww_prev, const float* __restrict__ usage_prev,
                            float* __restrict__ outh_ws,
                            float* __restrict__ ifa_ws, float* __restrict__ alloc_ws){
  __shared__ float sraw[480];
  __shared__ float sifa[480];
  __shared__ unsigned long long keys[1024];
  __shared__ float wtot[16];
  int b = blockIdx.x, t = threadIdx.x;
  int lane = t & 63, wid = t >> 6;
  if (t < 727){
    float s = (t < 471) ? b_if[t] : b_hid[t-471];
    #pragma unroll 8
    for (int kt = 0; kt < 32; ++kt) s += ifpart[((long)kt*16 + b)*768 + t];
    if (t < 471) sraw[t] = s;
    else         outh_ws[b*256 + (t-471)] = s;
  }
  __syncthreads();
  if (t < 459){
    float v = sraw[t], o = v;
    if ((t >= 256 && t < 260) || t == 324) o = 1.0f + softplusf(v);
    else if ((t >= 325 && t < 389) || (t >= 453 && t < 459)) o = sigf(v);
    sifa[t] = o;
  }
  if (t < 4){
    float p0 = sraw[459+t*3+0], p1 = sraw[459+t*3+1], p2 = sraw[459+t*3+2];
    float mx = fmaxf(p0, fmaxf(p1,p2));
    float e0 = expf(p0-mx), e1 = expf(p1-mx), e2 = expf(p2-mx);
    float s = e0+e1+e2;
    sifa[459+t*3+0]=e0/s; sifa[459+t*3+1]=e1/s; sifa[459+t*3+2]=e2/s;
  }
  __syncthreads();
  if (t < 471) ifa_ws[b*512 + t] = sifa[t];
  float f0 = sifa[453], f1 = sifa[454], f2 = sifa[455], f3 = sifa[456];
  float psi = (1.f - f0*rw_prev[(long)(b*4+0)*1024 + t])
            * (1.f - f1*rw_prev[(long)(b*4+1)*1024 + t])
            * (1.f - f2*rw_prev[(long)(b*4+2)*1024 + t])
            * (1.f - f3*rw_prev[(long)(b*4+3)*1024 + t]);
  float uu = usage_prev[b*1024+t], w = ww_prev[b*1024+t];
  float uval = (uu + w - uu*w) * psi;
  unsigned int ub = __float_as_uint(uval);
  unsigned int k32 = ub ^ (((int)ub >> 31) | 0x80000000u);
  unsigned long long key = ((unsigned long long)k32 << 32) | (unsigned int)t;
  for (int kk2 = 2; kk2 <= 1024; kk2 <<= 1){
    for (int j = kk2 >> 1; j > 0; j >>= 1){
      unsigned long long other;
      if (j >= 64){
        keys[t] = key;
        __syncthreads();
        other = keys[t ^ j];
        __syncthreads();
      } else {
        other = __shfl_xor(key, j);
      }
      bool up = ((t & kk2) == 0);
      bool keepMin = (((t & j) == 0) == up);
      if (keepMin ? (other < key) : (other > key)) key = other;
    }
  }
  unsigned int hk = (unsigned int)(key >> 32);
  unsigned int ob = (hk & 0x80000000u) ? (hk ^ 0x80000000u) : ~hk;
  float su = __uint_as_float(ob);
  int oi = (int)(key & 1023u);
  float s = su;
  #pragma unroll
  for (int off = 1; off < 64; off <<= 1){
    float v = __shfl_up(s, off);
    if (lane >= off) s *= v;
  }
  if (lane == 63) wtot[wid] = s;
  __syncthreads();
  float wpre = 1.0f;
  for (int w2 = 0; w2 < wid; ++w2) wpre *= wtot[w2];
  float ex = __shfl_up(s, 1);
  if (lane == 0) ex = 1.0f;
  float cpe = ex * wpre;
  alloc_ws[b*1024 + oi] = (1.0f - su) * cpe;
}

// ---------------- K4: write-content scores — grid (16 at,16 b), block 512 (8 waves x 8 rows) ----------------
__global__ __launch_bounds__(512) void k_wscore(const float* __restrict__ mem_prev,
    const float* __restrict__ ifa_ws, float* __restrict__ wsc_ws){
  int at = blockIdx.x, b = blockIdx.y;
  int t = threadIdx.x, w = t >> 6, m = t & 63;
  const float* ifa = ifa_ws + b*512;
  float kwm = ifa[260+m], beta = ifa[324];
  float knsq = kwm*kwm;
  for (int o = 32; o > 0; o >>= 1) knsq += __shfl_xor(knsq, o);
  float kn = sqrtf(knsq);
  for (int rr = 0; rr < 8; ++rr){
    int a = at*64 + w*8 + rr;
    float v = mem_prev[((long)b*1024+a)*64+m];
    float d = v*kwm, sq = v*v;
    for (int o = 32; o > 0; o >>= 1){ d += __shfl_xor(d,o); sq += __shfl_xor(sq,o); }
    if (m == 0) wsc_ws[b*1024+a] = beta*d/(kn*sqrtf(sq)+1e-6f);
  }
}

// ---------------- K5: softmax(wsc) + ww + e=ww*rw — grid 16, block 1024 (wave reduce) ----------------
__global__ void k_cw_ww(const float* __restrict__ wsc_ws, const float* __restrict__ ifa_ws,
                        const float* __restrict__ alloc_ws, const float* __restrict__ rw_prev,
                        float* __restrict__ ww_ws, float* __restrict__ e_ws){
  __shared__ float wred[16]; __shared__ float wred2[16];
  int b = blockIdx.x, t = threadIdx.x, lane = t & 63, wid = t >> 6;
  const float* ifa = ifa_ws + b*512;
  float g_a = ifa[457], g_w = ifa[458];
  float sc = wsc_ws[b*1024+t];
  float m = sc;
  for (int o = 32; o > 0; o >>= 1) m = fmaxf(m, __shfl_xor(m, o));
  if (lane == 0) wred[wid] = m;
  __syncthreads();
  float mx = wred[0];
  #pragma unroll
  for (int i = 1; i < 16; ++i) mx = fmaxf(mx, wred[i]);
  float e = expf(sc - mx);
  float ssum = e;
  for (int o = 32; o > 0; o >>= 1) ssum += __shfl_xor(ssum, o);
  if (lane == 0) wred2[wid] = ssum;
  __syncthreads();
  float tot = 0.0f;
  #pragma unroll
  for (int i = 0; i < 16; ++i) tot += wred2[i];
  float cw = e / tot;
  float ww = g_w*(g_a*alloc_ws[b*1024+t] + (1.0f-g_a)*cw);
  ww_ws[b*1024+t] = ww;
  #pragma unroll
  for (int r = 0; r < 4; ++r)
    e_ws[(long)(b*4+r)*1024 + t] = ww * rw_prev[(long)(b*4+r)*1024 + t];
}

// ---------------- K6: MERGED score + linkfb — grid 256+4096 = 4352, block 256 ----------------
__global__ __launch_bounds__(256) void k_slfb(const float* __restrict__ mem_prev,
    const float* __restrict__ ww_ws, const float* __restrict__ ifa_ws,
    float* __restrict__ mnorm_ws, float* __restrict__ rdot_ws,
    const float* __restrict__ link_prev, const float* __restrict__ rw_prev,
    const float* __restrict__ e_ws, const float* __restrict__ prec_prev,
    float* __restrict__ fwd_part, float* __restrict__ bwd_part){
  __shared__ float Lt[64][68];
  int bid = blockIdx.x, t = threadIdx.x;
  if (bid < 256){
    int at = bid & 15, b = bid >> 4;
    int w = t >> 6, m = t & 63;
    const float* ifa = ifa_ws + b*512;
    float er = ifa[325+m], wv = ifa[389+m];
    float k0 = ifa[m], k1 = ifa[64+m], k2 = ifa[128+m], k3 = ifa[192+m];
    for (int rr = 0; rr < 16; ++rr){
      int a = at*64 + w*16 + rr;
      float ww = ww_ws[b*1024+a];
      float v = mem_prev[((long)b*1024+a)*64+m]*(1.0f - ww*er) + ww*wv;
      float sq = v*v, d0 = v*k0, d1 = v*k1, d2 = v*k2, d3 = v*k3;
      for (int o = 32; o > 0; o >>= 1){
        sq += __shfl_xor(sq,o); d0 += __shfl_xor(d0,o); d1 += __shfl_xor(d1,o);
        d2 += __shfl_xor(d2,o); d3 += __shfl_xor(d3,o);
      }
      if (m == 0){
        mnorm_ws[b*1024+a] = sqrtf(sq);
        rdot_ws[(long)(b*4+0)*1024+a] = d0; rdot_ws[(long)(b*4+1)*1024+a] = d1;
        rdot_ws[(long)(b*4+2)*1024+a] = d2; rdot_ws[(long)(b*4+3)*1024+a] = d3;
      }
    }
    return;
  }
  int lb = bid - 256;
  int band = lb & 15, ct = (lb >> 4) & 15, b = lb >> 8;
  int r = t >> 6, lane = t & 63;
  int ru = __builtin_amdgcn_readfirstlane(r);
  const float4* L4 = (const float4*)link_prev;
  #pragma unroll
  for (int q = 0; q < 4; ++q){
    int idx = t + 256*q;
    int row = idx >> 4, c4 = idx & 15;
    float4 v = L4[((long)b << 18) + (long)(band*64+row)*256 + ct*16 + c4];
    *(float4*)&Lt[row][c4*4] = v;
  }
  const float* aJ = rw_prev + (long)(b*4+ru)*1024 + ct*64;
  const float* eJ = e_ws    + (long)(b*4+ru)*1024 + ct*64;
  const float* aI = rw_prev + (long)(b*4+ru)*1024 + band*64;
  const float* eI = e_ws    + (long)(b*4+ru)*1024 + band*64;
  float pv = prec_prev[b*1024 + ct*64 + lane] * aJ[lane];
  float wvs = eI[lane];
  for (int o = 32; o > 0; o >>= 1){ pv += __shfl_xor(pv,o); wvs += __shfl_xor(wvs,o); }
  float wwi = ww_ws[b*1024 + band*64 + lane];
  float wwc = ww_ws[b*1024 + ct*64 + lane];
  float pc  = prec_prev[b*1024 + ct*64 + lane];
  __syncthreads();
  float A1 = 0.0f, A2 = 0.0f;
  for (int jc = 0; jc < 64; jc += 4){
    float4 Lv = *(const float4*)&Lt[lane][jc];
    A1 += Lv.x*aJ[jc] + Lv.y*aJ[jc+1] + Lv.z*aJ[jc+2] + Lv.w*aJ[jc+3];
    A2 += Lv.x*eJ[jc] + Lv.y*eJ[jc+1] + Lv.z*eJ[jc+2] + Lv.w*eJ[jc+3];
  }
  float facc = (1.0f - wwi)*A1 - A2 + wwi*pv;
  float B1 = 0.0f, B2 = 0.0f;
  for (int rowl = 0; rowl < 64; ++rowl){
    float Lv = Lt[rowl][lane];
    B1 += Lv * aI[rowl];
    B2 += Lv * eI[rowl];
  }
  float bacc = (1.0f - wwc)*B1 - B2 + pc*wvs;
  if (band == ct){
    float D = ((1.0f - 2.0f*wwi)*Lt[lane][lane] + wwi*pc)*aJ[lane];
    facc -= D;
    bacc -= D;
  }
  fwd_part[(long)ct*65536 + (long)(b*4+r)*1024 + band*64 + lane] = facc;
  bwd_part[(long)band*65536 + (long)(b*4+r)*1024 + ct*64 + lane] = bacc;
}

// ---------------- K8: read softmax + mix + rv — grid (4,16), block 1024 ----------------
__global__ void k_read(const float* __restrict__ rdot_ws, const float* __restrict__ mnorm_ws,
                       const float* __restrict__ ifa_ws, const float* __restrict__ fwd_part,
                       const float* __restrict__ bwd_part, const float* __restrict__ mem_prev,
                       const float* __restrict__ ww_ws, float* __restrict__ rv_ws){
  __shared__ __align__(16) float red[1024];
  __shared__ __align__(16) float wrs[1024];
  __shared__ __align__(16) float wwsh[1024];
  __shared__ float par[1]; __shared__ float wred[16]; __shared__ float wred2[16];
  int r = blockIdx.x, b = blockIdx.y, t = threadIdx.x; // a = t
  int lane = t & 63, wid = t >> 6;
  const float* ifa = ifa_ws + b*512;
  long base = (long)(b*4+r)*1024 + t;
  float fsum = 0.0f, bsum = 0.0f;
  #pragma unroll
  for (int c = 0; c < 16; ++c){
    fsum += fwd_part[(long)c*65536 + base];
    bsum += bwd_part[(long)c*65536 + base];
  }
  if (t < 64){
    float v = ifa[r*64+t];
    float sq = v*v;
    for (int o = 32; o > 0; o >>= 1) sq += __shfl_xor(sq, o);
    if (t == 0) par[0] = sqrtf(sq);
  }
  wwsh[t] = ww_ws[b*1024+t];
  __syncthreads();
  float kn = par[0], beta = ifa[256 + r];
  float sc = beta * rdot_ws[base] / (kn*mnorm_ws[b*1024+t] + 1e-6f);
  float m = sc;
  for (int o = 32; o > 0; o >>= 1) m = fmaxf(m, __shfl_xor(m, o));
  if (lane == 0) wred[wid] = m;
  __syncthreads();
  float mx = wred[0];
  #pragma unroll
  for (int i = 1; i < 16; ++i) mx = fmaxf(mx, wred[i]);
  float e = expf(sc - mx);
  float s = e;
  for (int o = 32; o > 0; o >>= 1) s += __shfl_xor(s, o);
  if (lane == 0) wred2[wid] = s;
  __syncthreads();
  float tot = 0.0f;
  #pragma unroll
  for (int i = 0; i < 16; ++i) tot += wred2[i];
  float cr = e / tot;
  float p0 = ifa[459+3*r], p1 = ifa[460+3*r], p2 = ifa[461+3*r];
  wrs[t] = p0*bsum + p1*cr + p2*fsum;
  __syncthreads();
  int mm = t & 63, ch = t >> 6;
  float er = ifa[325+mm], wv = ifa[389+mm];
  const float* memb = mem_prev + (long)b*65536 + mm;
  float acc = 0;
  for (int q = 0; q < 64; q += 4){
    int a = ch*64 + q;
    float4 w4 = *(const float4*)&wwsh[a];
    float4 r4 = *(const float4*)&wrs[a];
    float v0 = memb[(long)(a+0)*64]*(1.0f - w4.x*er) + w4.x*wv;
    float v1 = memb[(long)(a+1)*64]*(1.0f - w4.y*er) + w4.y*wv;
    float v2 = memb[(long)(a+2)*64]*(1.0f - w4.z*er) + w4.z*wv;
    float v3 = memb[(long)(a+3)*64]*(1.0f - w4.w*er) + w4.w*wv;
    acc += r4.x*v0; acc += r4.y*v1; acc += r4.z*v2; acc += r4.w*v3;
  }
  red[ch*64 + mm] = acc;
  __syncthreads();
  if (t < 64){
    float s2 = 0;
    for (int c2 = 0; c2 < 16; ++c2) s2 += red[c2*64 + t];
    rv_ws[(b*4+r)*64 + t] = s2;
  }
}

// ---------------- K9: out = out_hidden + rv@W_rd + b_rd — grid 16, block 1024 (4-way K split) ----------------
__global__ void k_out(const float* __restrict__ outh_ws, const float* __restrict__ rv_ws,
                      const float* __restrict__ W_rd, const float* __restrict__ b_rd,
                      float* __restrict__ out){
  __shared__ float rvs[256]; __shared__ float part[4][256];
  int b = blockIdx.x, t = threadIdx.x;
  int o = t & 255, kq = t >> 8;
  if (t < 256) rvs[t] = rv_ws[b*256 + t];
  __syncthreads();
  float acc = 0.0f;
  for (int q = kq*64; q < kq*64 + 64; ++q) acc += rvs[q]*W_rd[(long)q*256 + o];
  part[kq][o] = acc;
  __syncthreads();
  if (t < 256)
    out[b*256+t] = outh_ws[b*256+t] + b_rd[t] + part[0][t] + part[1][t] + part[2][t] + part[3][t];
}

extern "C" void kernel_launch(void* const* d_in, const int* in_sizes, int n_in,
                              void* d_out, int out_size, void* d_ws, size_t ws_size,
                              hipStream_t stream){
  const float* x          = (const float*)d_in[0];
  const float* h_prev     = (const float*)d_in[1];
  const float* c_prev     = (const float*)d_in[2];
  const float* mem_prev   = (const float*)d_in[3];
  const float* rw_prev    = (const float*)d_in[4];
  const float* ww_prev    = (const float*)d_in[5];
  const float* usage_prev = (const float*)d_in[6];
  const float* prec_prev  = (const float*)d_in[7];
  const float* link_prev  = (const float*)d_in[8];
  const float* rv_prev    = (const float*)d_in[9];
  const float* Wx         = (const float*)d_in[10];
  const float* Wh         = (const float*)d_in[11];
  const float* b_lstm     = (const float*)d_in[12];
  const float* W_hid      = (const float*)d_in[13];
  const float* b_hid      = (const float*)d_in[14];
  const float* W_if       = (const float*)d_in[15];
  const float* b_if       = (const float*)d_in[16];
  const float* W_rd       = (const float*)d_in[17];
  const float* b_rd       = (const float*)d_in[18];
  float* out = (float*)d_out;

  // ws layout (floats), total 3760128 = 14.3 MB (zpart/ifpart doubled for 32-way K split)
  float* ws = (float*)d_ws;
  float* h_ws     = ws + 0;          // 8192
  float* ifa_ws   = ws + 8192;       // 8192
  float* outh_ws  = ws + 16384;      // 4096
  float* alloc_ws = ws + 20480;      // 16384
  float* ww_ws    = ws + 36864;      // 16384
  float* mnorm_ws = ws + 53248;      // 16384
  float* wsc_ws   = ws + 69632;      // 16384
  float* rv_ws    = ws + 86016;      // 4096
  float* rdot_ws  = ws + 90112;      // 65536
  float* e_ws     = ws + 155648;     // 65536
  float* zpart    = ws + 221184;     // 1048576 (32 kt x 16 b x 2048)
  float* ifpart   = ws + 1269760;    // 393216  (32 kt x 16 b x 768)
  float* fwd_part = ws + 1662976;    // 1048576 (16 ct x 65536)
  float* bwd_part = ws + 2711552;    // 1048576 (16 band x 65536)

  k_lstm_part<<<dim3(16,32),128,0,stream>>>(x, rv_prev, h_prev, Wx, Wh, zpart);
  k_lstm_fin<<<dim3(4,16),128,0,stream>>>(zpart, b_lstm, c_prev, h_ws);
  k_iface_part<<<dim3(6,32),128,0,stream>>>(h_ws, W_if, W_hid, ifpart);
  k_actfa<<<16,1024,0,stream>>>(ifpart, b_if, b_hid, rw_prev, ww_prev, usage_prev,
                                outh_ws, ifa_ws, alloc_ws);
  k_wscore<<<dim3(16,16),512,0,stream>>>(mem_prev, ifa_ws, wsc_ws);
  k_cw_ww<<<16,1024,0,stream>>>(wsc_ws, ifa_ws, alloc_ws, rw_prev, ww_ws, e_ws);
  k_slfb<<<4352,256,0,stream>>>(mem_prev, ww_ws, ifa_ws, mnorm_ws, rdot_ws,
                                link_prev, rw_prev, e_ws, prec_prev, fwd_part, bwd_part);
  k_read<<<dim3(4,16),1024,0,stream>>>(rdot_ws, mnorm_ws, ifa_ws, fwd_part, bwd_part,
                                       mem_prev, ww_ws, rv_ws);
  k_out<<<16,1024,0,stream>>>(outh_ws, rv_ws, W_rd, b_rd, out);
}